// Round 20
// baseline (207.611 us; speedup 1.0000x reference)
//
#include <hip/hip_runtime.h>
#include <hip/hip_bf16.h>

typedef __bf16 bf16;
typedef bf16 bf16x8 __attribute__((ext_vector_type(8)));
typedef bf16 bf16x4 __attribute__((ext_vector_type(4)));
typedef float f32x4 __attribute__((ext_vector_type(4)));

__device__ __forceinline__ int SZ(int a) { return a ^ (((a >> 7) & 7) << 4); }

__global__ __launch_bounds__(256) void k_pre(const float* __restrict__ cW1,
    const float* __restrict__ cW2, const float* __restrict__ cW3,
    bf16* __restrict__ W1p, bf16* __restrict__ W2p, bf16* __restrict__ W3p) {
  const int bid = blockIdx.x, tid = threadIdx.x;
  if (bid < 32) {
    int i = bid * 256 + tid;            // W1: [oc][ky][kx][ic]
    int oc = i >> 8, k = i & 255;
    int ic = k & 3, kp = k >> 2, kx = kp & 7, ky = kp >> 3;
    W1p[i] = (bf16)cW1[oc * 256 + ic * 64 + ky * 8 + kx];
  } else if (bid < 160) {
    int i = (bid - 32) * 256 + tid;     // W2: [oc][ky][kx][ic]
    int oc = i >> 9, k = i & 511;
    int ic = k & 31, kp = k >> 5, kx = kp & 3, ky = kp >> 2;
    W2p[i] = (bf16)cW2[oc * 512 + ic * 16 + ky * 4 + kx];
  } else {
    int i = (bid - 160) * 256 + tid;    // W3: [oc][ky][kx][ic]
    if (i < 36864) {
      int oc = i / 576, k = i - oc * 576;
      int ic = k & 63, kp = k >> 6, kx = kp % 3, ky = kp / 3;
      W3p[i] = (bf16)cW3[oc * 576 + ic * 9 + ky * 3 + kx];
    }
  }
}

__global__ __launch_bounds__(1024) void k_route_scan(const int* __restrict__ ecls,
    int* __restrict__ perm, int* __restrict__ cnt) {
  const int tid = threadIdx.x;
  const int4 ev = ((const int4*)ecls)[tid];
  int e[4] = {ev.x, ev.y, ev.z, ev.w};
  int lc[4] = {0, 0, 0, 0};
  #pragma unroll
  for (int i = 0; i < 4; ++i) lc[e[i]]++;
  const int lane = tid & 63, wv = tid >> 6;
  __shared__ int wsum[16][4];
  __shared__ int wbase[16][4];
  int pre[4];
  #pragma unroll
  for (int q = 0; q < 4; ++q) {
    int v = lc[q];
    #pragma unroll
    for (int d = 1; d < 64; d <<= 1) {
      int u = __shfl_up(v, d);
      if (lane >= d) v += u;
    }
    pre[q] = v - lc[q];
    if (lane == 63) wsum[wv][q] = v;
  }
  __syncthreads();
  if (tid == 0) {
    int tot[4] = {0, 0, 0, 0};
    for (int w = 0; w < 16; ++w)
      #pragma unroll
      for (int q = 0; q < 4; ++q) { wbase[w][q] = tot[q]; tot[q] += wsum[w][q]; }
    #pragma unroll
    for (int q = 0; q < 4; ++q) cnt[q] = tot[q];
  }
  __syncthreads();
  int run[4];
  #pragma unroll
  for (int q = 0; q < 4; ++q) run[q] = wbase[wv][q] + pre[q];
  #pragma unroll
  for (int i = 0; i < 4; ++i) {
    const int b = tid * 4 + i;
    perm[e[i] * 4096 + run[e[i]]] = b;
    run[e[i]]++;
  }
}

// FUSED FRONT: bid<16 route_cls | bid<1040 W1T transpose | else conv123 (r16 body)
__global__ __launch_bounds__(256, 3) void k_front(const float* __restrict__ x,
    const float* __restrict__ bd, int* __restrict__ ecls,
    const float* __restrict__ aW1, const float* __restrict__ vW1, bf16* __restrict__ W1T,
    const bf16* __restrict__ W1p, const float* __restrict__ b1,
    const bf16* __restrict__ W2p, const float* __restrict__ b2,
    const bf16* __restrict__ W3p, const float* __restrict__ b3,
    bf16* __restrict__ h3) {
  __shared__ bf16 sA[16384];
  __shared__ bf16 sh1[9000];
  const int bid = blockIdx.x, tid = threadIdx.x;

  if (bid < 16) {
    const int b = bid * 256 + tid;
    const float r = x[(size_t)b * 16384 + 12288];
    ecls[b] = (r > bd[0]) + (r > bd[1]) + (r > bd[2]);
    return;
  }
  if (bid < 1040) {
    float* t = (float*)sA;
    const int bid2 = bid - 16;
    const int bz = bid2 >> 7, rest = bid2 & 127, by = rest >> 4, bx = rest & 15;
    const float* in = (bz >= 4 ? vW1 : aW1) + (size_t)(bz & 3) * 524288;
    const int k0 = bx * 64, n0 = by * 64;
    const int cc = tid & 63, r0 = (tid >> 6) * 16;
    for (int i = 0; i < 16; ++i)
      t[(r0 + i) * 65 + cc] = in[(size_t)(k0 + r0 + i) * 512 + n0 + cc];
    __syncthreads();
    for (int i = 0; i < 16; ++i) {
      int n = r0 + i, k = cc;
      W1T[((size_t)bz * 512 + n0 + n) * 1024 + k0 + k] = (bf16)t[k * 65 + n];
    }
    return;
  }

  const int b = bid - 1040;
  const int lane = tid & 63, wave = tid >> 6, lid = lane & 15, c = lane >> 4;

  {
    bf16x8 bw[8];
    const int ot = wave & 1, col = ot * 16 + lid;
    #pragma unroll
    for (int ks = 0; ks < 8; ++ks) bw[ks] = *(const bf16x8*)(W1p + col * 256 + ks * 32 + c * 8);
    const float bias = b1[col];
    #pragma unroll
    for (int ks = 0; ks < 8; ++ks) asm volatile("" : "+v"(bw[ks]));

    const float4* xs = (const float4*)(x + (size_t)b * 16384);
    #pragma unroll
    for (int hb = 0; hb < 2; ++hb) {
      float4 r[2][4];
      #pragma unroll
      for (int h = 0; h < 2; ++h)
        #pragma unroll
        for (int ic = 0; ic < 4; ++ic)
          r[h][ic] = xs[ic * 1024 + tid + (hb * 2 + h) * 256];
      #pragma unroll
      for (int h = 0; h < 2; ++h) {
        const int g = tid + (hb * 2 + h) * 256;
        bf16x8 lo, hi;
        lo[0] = (bf16)r[h][0].x; lo[1] = (bf16)r[h][1].x; lo[2] = (bf16)r[h][2].x; lo[3] = (bf16)r[h][3].x;
        lo[4] = (bf16)r[h][0].y; lo[5] = (bf16)r[h][1].y; lo[6] = (bf16)r[h][2].y; lo[7] = (bf16)r[h][3].y;
        hi[0] = (bf16)r[h][0].z; hi[1] = (bf16)r[h][1].z; hi[2] = (bf16)r[h][2].z; hi[3] = (bf16)r[h][3].z;
        hi[4] = (bf16)r[h][0].w; hi[5] = (bf16)r[h][1].w; hi[6] = (bf16)r[h][2].w; hi[7] = (bf16)r[h][3].w;
        *(bf16x8*)((char*)sA + SZ(g * 32))      = lo;
        *(bf16x8*)((char*)sA + SZ(g * 32 + 16)) = hi;
      }
    }
    __syncthreads();

    int ab[8], ptv[8];
    #pragma unroll
    for (int pi = 0; pi < 8; ++pi) {
      int pt = (wave >> 1) + 2 * pi; if (pt > 14) pt = 14;
      ptv[pi] = pt;
      int p = pt * 16 + lid; if (p > 224) p = 224;
      const int py = p / 15, px = p - py * 15;
      ab[pi] = py * 2048 + px * 32 + c * 16;
    }
    f32x4 acc[8];
    #pragma unroll
    for (int pi = 0; pi < 8; ++pi) acc[pi] = (f32x4){0.f, 0.f, 0.f, 0.f};
    #pragma unroll
    for (int ks = 0; ks < 8; ++ks)
      #pragma unroll
      for (int pi = 0; pi < 8; ++pi)
        acc[pi] = __builtin_amdgcn_mfma_f32_16x16x32_bf16(
            *(const bf16x8*)((const char*)sA + SZ(ab[pi] + ks * 512)), bw[ks], acc[pi], 0, 0, 0);
    __syncthreads();
    #pragma unroll
    for (int pi = 0; pi < 8; ++pi)
      #pragma unroll
      for (int r = 0; r < 4; ++r) {
        const int pr = ptv[pi] * 16 + c * 4 + r;
        if (pr < 225) sh1[pr * 40 + col] = (bf16)fmaxf(acc[pi][r] + bias, 0.f);
      }
  }
  __syncthreads();

  bf16* sh2 = sA;
  const int col = wave * 16 + lid;
  {
    bf16x8 bw2[16];
    #pragma unroll
    for (int ks = 0; ks < 16; ++ks) bw2[ks] = *(const bf16x8*)(W2p + col * 512 + ks * 32 + c * 8);
    const float bias2 = b2[col];
    #pragma unroll
    for (int ks = 0; ks < 16; ++ks) asm volatile("" : "+v"(bw2[ks]));

    int abase[3];
    #pragma unroll
    for (int pt = 0; pt < 3; ++pt) {
      int p = pt * 16 + lid; if (p > 35) p = 35;
      const int oy = p / 6, ox = p - oy * 6;
      abase[pt] = (oy * 30 + ox * 2) * 40 + c * 8;
    }
    f32x4 acc2[3];
    #pragma unroll
    for (int pt = 0; pt < 3; ++pt) acc2[pt] = (f32x4){0.f, 0.f, 0.f, 0.f};
    #pragma unroll
    for (int ks = 0; ks < 16; ++ks) {
      const int ky = ks >> 2, kx = ks & 3;
      #pragma unroll
      for (int pt = 0; pt < 3; ++pt)
        acc2[pt] = __builtin_amdgcn_mfma_f32_16x16x32_bf16(
            *(const bf16x8*)(&sh1[abase[pt] + (ky * 15 + kx) * 40]), bw2[ks], acc2[pt], 0, 0, 0);
    }
    #pragma unroll
    for (int pt = 0; pt < 3; ++pt)
      #pragma unroll
      for (int r = 0; r < 4; ++r) {
        const int pr = pt * 16 + c * 4 + r;
        if (pr < 36) sh2[pr * 72 + col] = (bf16)fmaxf(acc2[pt][r] + bias2, 0.f);
      }
  }
  __syncthreads();

  {
    bf16x8 bw3[18];
    #pragma unroll
    for (int ks = 0; ks < 18; ++ks) bw3[ks] = *(const bf16x8*)(W3p + col * 576 + ks * 32 + c * 8);
    const float bias3 = b3[col];
    #pragma unroll
    for (int ks = 0; ks < 18; ++ks) asm volatile("" : "+v"(bw3[ks]));
    const int oy = lid >> 2, ox = lid & 3;
    const int ab3 = (oy * 6 + ox) * 72 + c * 8;
    f32x4 acc = {0.f, 0.f, 0.f, 0.f};
    #pragma unroll
    for (int ks = 0; ks < 18; ++ks) {
      const int kp = ks >> 1, ky = kp / 3, kx = kp - ky * 3;
      acc = __builtin_amdgcn_mfma_f32_16x16x32_bf16(
          *(const bf16x8*)(&sh2[ab3 + (ky * 6 + kx) * 72 + (ks & 1) * 32]), bw3[ks], acc, 0, 0, 0);
    }
    bf16x4 o;
    #pragma unroll
    for (int r = 0; r < 4; ++r) o[r] = (bf16)fmaxf(acc[r] + bias3, 0.f);
    *(bf16x4*)(h3 + (size_t)b * 1024 + col * 16 + c * 4) = o;
  }
}

// MLP L1: N-tile 64 (grid y=8) -> ~512 active blocks = 2/CU for latency hiding.
// Waves 2M x 4N of 32x16; per-wave B reuse 2 MFMA per 16B load.
__global__ __launch_bounds__(512) void k_mlp1(const bf16* __restrict__ h3,
    const bf16* __restrict__ W1T, const float* __restrict__ ab1, const float* __restrict__ vb1,
    const int* __restrict__ perm, const int* __restrict__ cnt,
    bf16* __restrict__ za, bf16* __restrict__ zv) {
  const int e = blockIdx.z;
  const int cntE = cnt[e];
  const int m0 = blockIdx.x * 64;
  if (m0 >= cntE) return;
  const int n0 = blockIdx.y * 64;
  const bf16* WA = W1T + (size_t)e * 524288;
  const bf16* WV = W1T + (size_t)(4 + e) * 524288;

  __shared__ bf16 As[64 * 72];
  __shared__ int rows[64];
  const int tid = threadIdx.x;
  if (tid < 64) {
    int j = m0 + tid; if (j > cntE - 1) j = cntE - 1;
    rows[tid] = perm[e * 4096 + j];
  }
  __syncthreads();

  const int lane = tid & 63, wave = tid >> 6;
  const int lid = lane & 15, c = lane >> 4;
  const int wm = wave >> 2, wn = wave & 3;
  const int srow = tid >> 3, skoff = (tid & 7) * 8;
  const bf16* arow = h3 + (size_t)rows[srow] * 1024 + skoff;
  const int colA = n0 + wn * 16 + lid;
  const bf16* wa0 = WA + (size_t)colA * 1024 + c * 8;
  const bf16* wv0 = WV + (size_t)colA * 1024 + c * 8;
  const int ar0 = (wm * 32 + lid) * 72 + c * 8;
  const int ar1 = (wm * 32 + 16 + lid) * 72 + c * 8;

  f32x4 acc[2][2];   // [net][mf]
  #pragma unroll
  for (int n = 0; n < 2; ++n)
    #pragma unroll
    for (int m = 0; m < 2; ++m) acc[n][m] = (f32x4){0.f, 0.f, 0.f, 0.f};

  for (int k0 = 0; k0 < 1024; k0 += 64) {
    *(bf16x8*)(&As[srow * 72 + skoff]) = *(const bf16x8*)(arow + k0);
    __syncthreads();
    bf16x8 a[2][2];
    #pragma unroll
    for (int m = 0; m < 2; ++m)
      #pragma unroll
      for (int ks = 0; ks < 2; ++ks)
        a[m][ks] = *(const bf16x8*)(&As[(m ? ar1 : ar0) + ks * 32]);
    #pragma unroll
    for (int ks = 0; ks < 2; ++ks) {
      bf16x8 bA = *(const bf16x8*)(wa0 + k0 + ks * 32);
      bf16x8 bV = *(const bf16x8*)(wv0 + k0 + ks * 32);
      #pragma unroll
      for (int m = 0; m < 2; ++m) {
        acc[0][m] = __builtin_amdgcn_mfma_f32_16x16x32_bf16(a[m][ks], bA, acc[0][m], 0, 0, 0);
        acc[1][m] = __builtin_amdgcn_mfma_f32_16x16x32_bf16(a[m][ks], bV, acc[1][m], 0, 0, 0);
      }
    }
    __syncthreads();
  }

  {
    const float bA = ab1[e * 512 + colA];
    const float bV = vb1[e * 512 + colA];
    #pragma unroll
    for (int m = 0; m < 2; ++m)
      #pragma unroll
      for (int r = 0; r < 4; ++r) {
        const int ridx = wm * 32 + m * 16 + c * 4 + r;
        if (m0 + ridx < cntE) {
          const size_t zoff = (size_t)rows[ridx] * 512 + colA;
          za[zoff] = (bf16)fmaxf(acc[0][m][r] + bA, 0.f);
          zv[zoff] = (bf16)fmaxf(acc[1][m][r] + bV, 0.f);
        }
      }
  }
}

// MLP L2: M-tile 32 (grid x=128) -> 128 active blocks; waves 0-1 compute, all stage.
__global__ __launch_bounds__(256) void k_mlp2(const bf16* __restrict__ za,
    const bf16* __restrict__ zv,
    const float* __restrict__ aW2, const float* __restrict__ ab2,
    const float* __restrict__ vW2, const float* __restrict__ vb2,
    const int* __restrict__ perm, const int* __restrict__ cnt,
    float* __restrict__ out) {
  const int e = blockIdx.y;
  const int cntE = cnt[e];
  const int m0 = blockIdx.x * 32;
  if (m0 >= cntE) return;
  __shared__ bf16 Bs[48 * 520];
  const int tid = threadIdx.x;
  for (int i = tid; i < 512 * 32; i += 256) {
    const int k = i >> 5, n = i & 31;
    Bs[n * 520 + k] = (bf16)aW2[(size_t)e * 16384 + i];
  }
  for (int i = tid; i < 512; i += 256) Bs[32 * 520 + i] = (bf16)vW2[e * 512 + i];
  for (int i = tid; i < 15 * 512; i += 256) {
    const int n = 33 + (i >> 9), k = i & 511;
    Bs[n * 520 + k] = (bf16)0.f;
  }
  __syncthreads();

  const int lane = tid & 63, wave = tid >> 6;
  const int lid = lane & 15, c = lane >> 4;
  if (wave >= 2) return;
  const int row0 = m0 + wave * 16;
  if (row0 >= cntE) return;
  int rowl = row0 + lid; if (rowl > cntE - 1) rowl = cntE - 1;
  const int pb = perm[e * 4096 + rowl];
  const bf16* aA = za + (size_t)pb * 512 + c * 8;
  const bf16* aV = zv + (size_t)pb * 512 + c * 8;

  f32x4 acc0 = {0.f, 0.f, 0.f, 0.f}, acc1 = acc0, accv = acc0;
  #pragma unroll
  for (int k0 = 0; k0 < 512; k0 += 32) {
    bf16x8 a1 = *(const bf16x8*)(aA + k0);
    bf16x8 a2 = *(const bf16x8*)(aV + k0);
    bf16x8 b0 = *(const bf16x8*)(&Bs[lid * 520 + k0 + c * 8]);
    bf16x8 b1 = *(const bf16x8*)(&Bs[(16 + lid) * 520 + k0 + c * 8]);
    bf16x8 b2 = *(const bf16x8*)(&Bs[(32 + lid) * 520 + k0 + c * 8]);
    acc0 = __builtin_amdgcn_mfma_f32_16x16x32_bf16(a1, b0, acc0, 0, 0, 0);
    acc1 = __builtin_amdgcn_mfma_f32_16x16x32_bf16(a1, b1, acc1, 0, 0, 0);
    accv = __builtin_amdgcn_mfma_f32_16x16x32_bf16(a2, b2, accv, 0, 0, 0);
  }

  const float ba0 = ab2[e * 32 + lid], ba1 = ab2[e * 32 + 16 + lid], bv = vb2[e];
  #pragma unroll
  for (int r = 0; r < 4; ++r) {
    const int row = row0 + c * 4 + r;
    const float y0 = acc0[r] + ba0, y1 = acc1[r] + ba1;
    float s = y0 + y1;
    s += __shfl_xor(s, 1); s += __shfl_xor(s, 2);
    s += __shfl_xor(s, 4); s += __shfl_xor(s, 8);
    const float mean = s * 0.03125f;
    const float ys = __shfl(accv[r], lane & 48) + bv;
    if (row < cntE) {
      const int bq = perm[e * 4096 + row];
      out[(size_t)bq * 32 + lid] = y0 - mean + ys;
      out[(size_t)bq * 32 + 16 + lid] = y1 - mean + ys;
    }
  }
}

extern "C" void kernel_launch(void* const* d_in, const int* in_sizes, int n_in,
                              void* d_out, int out_size, void* d_ws, size_t ws_size,
                              hipStream_t stream) {
  const float* x   = (const float*)d_in[0];
  const float* cW1 = (const float*)d_in[1];
  const float* cb1 = (const float*)d_in[2];
  const float* cW2 = (const float*)d_in[3];
  const float* cb2 = (const float*)d_in[4];
  const float* cW3 = (const float*)d_in[5];
  const float* cb3 = (const float*)d_in[6];
  const float* aW1 = (const float*)d_in[7];
  const float* ab1 = (const float*)d_in[8];
  const float* aW2 = (const float*)d_in[9];
  const float* ab2 = (const float*)d_in[10];
  const float* vW1 = (const float*)d_in[11];
  const float* vb1 = (const float*)d_in[12];
  const float* vW2 = (const float*)d_in[13];
  const float* vb2 = (const float*)d_in[14];
  const float* bd  = (const float*)d_in[15];
  float* out = (float*)d_out;

  char* ws = (char*)d_ws;
  bf16* W1T = (bf16*)(ws);                          // 8,388,608
  bf16* za  = (bf16*)(ws + 8388608ull);             // 4,194,304
  bf16* zv  = (bf16*)(ws + 12582912ull);            // 4,194,304
  bf16* h3  = (bf16*)(ws + 16777216ull);            // 8,388,608
  bf16* W1p = (bf16*)(ws + 25165824ull);            // 16,384
  bf16* W2p = (bf16*)(ws + 25182208ull);            // 65,536
  bf16* W3p = (bf16*)(ws + 25247744ull);            // 73,728
  int* perm = (int*)(ws + 25321472ull);             // 65,536
  int* cnt  = (int*)(ws + 25387008ull);             // 64
  int* ecls = (int*)(ws + 25387072ull);             // 16,384

  k_pre<<<304, 256, 0, stream>>>(cW1, cW2, cW3, W1p, W2p, W3p);
  k_front<<<5136, 256, 0, stream>>>(x, bd, ecls, aW1, vW1, W1T,
                                    W1p, cb1, W2p, cb2, W3p, cb3, h3);
  k_route_scan<<<1, 1024, 0, stream>>>(ecls, perm, cnt);
  k_mlp1<<<dim3(64, 8, 4), 512, 0, stream>>>(h3, W1T, ab1, vb1, perm, cnt, za, zv);
  k_mlp2<<<dim3(128, 4), 256, 0, stream>>>(za, zv, aW2, ab2, vW2, vb2, perm, cnt, out);
}

// Round 21
// 200.416 us; speedup vs baseline: 1.0359x; 1.0359x over previous
//
#include <hip/hip_runtime.h>
#include <hip/hip_bf16.h>

typedef __bf16 bf16;
typedef bf16 bf16x8 __attribute__((ext_vector_type(8)));
typedef bf16 bf16x4 __attribute__((ext_vector_type(4)));
typedef float f32x4 __attribute__((ext_vector_type(4)));

__device__ __forceinline__ int SZ(int a) { return a ^ (((a >> 7) & 7) << 4); }

__global__ __launch_bounds__(256) void k_pre(const float* __restrict__ cW1,
    const float* __restrict__ cW2, const float* __restrict__ cW3,
    bf16* __restrict__ W1p, bf16* __restrict__ W2p, bf16* __restrict__ W3p) {
  const int bid = blockIdx.x, tid = threadIdx.x;
  if (bid < 32) {
    int i = bid * 256 + tid;            // W1: [oc][ky][kx][ic]
    int oc = i >> 8, k = i & 255;
    int ic = k & 3, kp = k >> 2, kx = kp & 7, ky = kp >> 3;
    W1p[i] = (bf16)cW1[oc * 256 + ic * 64 + ky * 8 + kx];
  } else if (bid < 160) {
    int i = (bid - 32) * 256 + tid;     // W2: [oc][ky][kx][ic]
    int oc = i >> 9, k = i & 511;
    int ic = k & 31, kp = k >> 5, kx = kp & 3, ky = kp >> 2;
    W2p[i] = (bf16)cW2[oc * 512 + ic * 16 + ky * 4 + kx];
  } else {
    int i = (bid - 160) * 256 + tid;    // W3: [oc][ky][kx][ic]
    if (i < 36864) {
      int oc = i / 576, k = i - oc * 576;
      int ic = k & 63, kp = k >> 6, kx = kp % 3, ky = kp / 3;
      W3p[i] = (bf16)cW3[oc * 576 + ic * 9 + ky * 3 + kx];
    }
  }
}

__global__ __launch_bounds__(1024) void k_route_scan(const int* __restrict__ ecls,
    int* __restrict__ perm, int* __restrict__ cnt) {
  const int tid = threadIdx.x;
  const int4 ev = ((const int4*)ecls)[tid];
  int e[4] = {ev.x, ev.y, ev.z, ev.w};
  int lc[4] = {0, 0, 0, 0};
  #pragma unroll
  for (int i = 0; i < 4; ++i) lc[e[i]]++;
  const int lane = tid & 63, wv = tid >> 6;
  __shared__ int wsum[16][4];
  __shared__ int wbase[16][4];
  int pre[4];
  #pragma unroll
  for (int q = 0; q < 4; ++q) {
    int v = lc[q];
    #pragma unroll
    for (int d = 1; d < 64; d <<= 1) {
      int u = __shfl_up(v, d);
      if (lane >= d) v += u;
    }
    pre[q] = v - lc[q];
    if (lane == 63) wsum[wv][q] = v;
  }
  __syncthreads();
  if (tid == 0) {
    int tot[4] = {0, 0, 0, 0};
    for (int w = 0; w < 16; ++w)
      #pragma unroll
      for (int q = 0; q < 4; ++q) { wbase[w][q] = tot[q]; tot[q] += wsum[w][q]; }
    #pragma unroll
    for (int q = 0; q < 4; ++q) cnt[q] = tot[q];
  }
  __syncthreads();
  int run[4];
  #pragma unroll
  for (int q = 0; q < 4; ++q) run[q] = wbase[wv][q] + pre[q];
  #pragma unroll
  for (int i = 0; i < 4; ++i) {
    const int b = tid * 4 + i;
    perm[e[i] * 4096 + run[e[i]]] = b;
    run[e[i]]++;
  }
}

// FUSED FRONT: bid<16 route_cls | bid<1040 W1T transpose | else conv123 (r16 body)
__global__ __launch_bounds__(256, 3) void k_front(const float* __restrict__ x,
    const float* __restrict__ bd, int* __restrict__ ecls,
    const float* __restrict__ aW1, const float* __restrict__ vW1, bf16* __restrict__ W1T,
    const bf16* __restrict__ W1p, const float* __restrict__ b1,
    const bf16* __restrict__ W2p, const float* __restrict__ b2,
    const bf16* __restrict__ W3p, const float* __restrict__ b3,
    bf16* __restrict__ h3) {
  __shared__ bf16 sA[16384];
  __shared__ bf16 sh1[9000];
  const int bid = blockIdx.x, tid = threadIdx.x;

  if (bid < 16) {
    const int b = bid * 256 + tid;
    const float r = x[(size_t)b * 16384 + 12288];
    ecls[b] = (r > bd[0]) + (r > bd[1]) + (r > bd[2]);
    return;
  }
  if (bid < 1040) {
    float* t = (float*)sA;
    const int bid2 = bid - 16;
    const int bz = bid2 >> 7, rest = bid2 & 127, by = rest >> 4, bx = rest & 15;
    const float* in = (bz >= 4 ? vW1 : aW1) + (size_t)(bz & 3) * 524288;
    const int k0 = bx * 64, n0 = by * 64;
    const int cc = tid & 63, r0 = (tid >> 6) * 16;
    for (int i = 0; i < 16; ++i)
      t[(r0 + i) * 65 + cc] = in[(size_t)(k0 + r0 + i) * 512 + n0 + cc];
    __syncthreads();
    for (int i = 0; i < 16; ++i) {
      int n = r0 + i, k = cc;
      W1T[((size_t)bz * 512 + n0 + n) * 1024 + k0 + k] = (bf16)t[k * 65 + n];
    }
    return;
  }

  const int b = bid - 1040;
  const int lane = tid & 63, wave = tid >> 6, lid = lane & 15, c = lane >> 4;

  {
    bf16x8 bw[8];
    const int ot = wave & 1, col = ot * 16 + lid;
    #pragma unroll
    for (int ks = 0; ks < 8; ++ks) bw[ks] = *(const bf16x8*)(W1p + col * 256 + ks * 32 + c * 8);
    const float bias = b1[col];
    #pragma unroll
    for (int ks = 0; ks < 8; ++ks) asm volatile("" : "+v"(bw[ks]));

    const float4* xs = (const float4*)(x + (size_t)b * 16384);
    #pragma unroll
    for (int hb = 0; hb < 2; ++hb) {
      float4 r[2][4];
      #pragma unroll
      for (int h = 0; h < 2; ++h)
        #pragma unroll
        for (int ic = 0; ic < 4; ++ic)
          r[h][ic] = xs[ic * 1024 + tid + (hb * 2 + h) * 256];
      #pragma unroll
      for (int h = 0; h < 2; ++h) {
        const int g = tid + (hb * 2 + h) * 256;
        bf16x8 lo, hi;
        lo[0] = (bf16)r[h][0].x; lo[1] = (bf16)r[h][1].x; lo[2] = (bf16)r[h][2].x; lo[3] = (bf16)r[h][3].x;
        lo[4] = (bf16)r[h][0].y; lo[5] = (bf16)r[h][1].y; lo[6] = (bf16)r[h][2].y; lo[7] = (bf16)r[h][3].y;
        hi[0] = (bf16)r[h][0].z; hi[1] = (bf16)r[h][1].z; hi[2] = (bf16)r[h][2].z; hi[3] = (bf16)r[h][3].z;
        hi[4] = (bf16)r[h][0].w; hi[5] = (bf16)r[h][1].w; hi[6] = (bf16)r[h][2].w; hi[7] = (bf16)r[h][3].w;
        *(bf16x8*)((char*)sA + SZ(g * 32))      = lo;
        *(bf16x8*)((char*)sA + SZ(g * 32 + 16)) = hi;
      }
    }
    __syncthreads();

    int ab[8], ptv[8];
    #pragma unroll
    for (int pi = 0; pi < 8; ++pi) {
      int pt = (wave >> 1) + 2 * pi; if (pt > 14) pt = 14;
      ptv[pi] = pt;
      int p = pt * 16 + lid; if (p > 224) p = 224;
      const int py = p / 15, px = p - py * 15;
      ab[pi] = py * 2048 + px * 32 + c * 16;
    }
    f32x4 acc[8];
    #pragma unroll
    for (int pi = 0; pi < 8; ++pi) acc[pi] = (f32x4){0.f, 0.f, 0.f, 0.f};
    #pragma unroll
    for (int ks = 0; ks < 8; ++ks)
      #pragma unroll
      for (int pi = 0; pi < 8; ++pi)
        acc[pi] = __builtin_amdgcn_mfma_f32_16x16x32_bf16(
            *(const bf16x8*)((const char*)sA + SZ(ab[pi] + ks * 512)), bw[ks], acc[pi], 0, 0, 0);
    __syncthreads();
    #pragma unroll
    for (int pi = 0; pi < 8; ++pi)
      #pragma unroll
      for (int r = 0; r < 4; ++r) {
        const int pr = ptv[pi] * 16 + c * 4 + r;
        if (pr < 225) sh1[pr * 40 + col] = (bf16)fmaxf(acc[pi][r] + bias, 0.f);
      }
  }
  __syncthreads();

  bf16* sh2 = sA;
  const int col = wave * 16 + lid;
  {
    bf16x8 bw2[16];
    #pragma unroll
    for (int ks = 0; ks < 16; ++ks) bw2[ks] = *(const bf16x8*)(W2p + col * 512 + ks * 32 + c * 8);
    const float bias2 = b2[col];
    #pragma unroll
    for (int ks = 0; ks < 16; ++ks) asm volatile("" : "+v"(bw2[ks]));

    int abase[3];
    #pragma unroll
    for (int pt = 0; pt < 3; ++pt) {
      int p = pt * 16 + lid; if (p > 35) p = 35;
      const int oy = p / 6, ox = p - oy * 6;
      abase[pt] = (oy * 30 + ox * 2) * 40 + c * 8;
    }
    f32x4 acc2[3];
    #pragma unroll
    for (int pt = 0; pt < 3; ++pt) acc2[pt] = (f32x4){0.f, 0.f, 0.f, 0.f};
    #pragma unroll
    for (int ks = 0; ks < 16; ++ks) {
      const int ky = ks >> 2, kx = ks & 3;
      #pragma unroll
      for (int pt = 0; pt < 3; ++pt)
        acc2[pt] = __builtin_amdgcn_mfma_f32_16x16x32_bf16(
            *(const bf16x8*)(&sh1[abase[pt] + (ky * 15 + kx) * 40]), bw2[ks], acc2[pt], 0, 0, 0);
    }
    #pragma unroll
    for (int pt = 0; pt < 3; ++pt)
      #pragma unroll
      for (int r = 0; r < 4; ++r) {
        const int pr = pt * 16 + c * 4 + r;
        if (pr < 36) sh2[pr * 72 + col] = (bf16)fmaxf(acc2[pt][r] + bias2, 0.f);
      }
  }
  __syncthreads();

  {
    bf16x8 bw3[18];
    #pragma unroll
    for (int ks = 0; ks < 18; ++ks) bw3[ks] = *(const bf16x8*)(W3p + col * 576 + ks * 32 + c * 8);
    const float bias3 = b3[col];
    #pragma unroll
    for (int ks = 0; ks < 18; ++ks) asm volatile("" : "+v"(bw3[ks]));
    const int oy = lid >> 2, ox = lid & 3;
    const int ab3 = (oy * 6 + ox) * 72 + c * 8;
    f32x4 acc = {0.f, 0.f, 0.f, 0.f};
    #pragma unroll
    for (int ks = 0; ks < 18; ++ks) {
      const int kp = ks >> 1, ky = kp / 3, kx = kp - ky * 3;
      acc = __builtin_amdgcn_mfma_f32_16x16x32_bf16(
          *(const bf16x8*)(&sh2[ab3 + (ky * 6 + kx) * 72 + (ks & 1) * 32]), bw3[ks], acc, 0, 0, 0);
    }
    bf16x4 o;
    #pragma unroll
    for (int r = 0; r < 4; ++r) o[r] = (bf16)fmaxf(acc[r] + bias3, 0.f);
    *(bf16x4*)(h3 + (size_t)b * 1024 + col * 16 + c * 4) = o;
  }
}

__global__ __launch_bounds__(512) void k_mlp1(const bf16* __restrict__ h3,
    const bf16* __restrict__ W1T, const float* __restrict__ ab1, const float* __restrict__ vb1,
    const int* __restrict__ perm, const int* __restrict__ cnt,
    bf16* __restrict__ za, bf16* __restrict__ zv) {
  const int e = blockIdx.z;
  const int cntE = cnt[e];
  const int m0 = blockIdx.x * 64;
  if (m0 >= cntE) return;
  const int n0 = blockIdx.y * 128;
  const bf16* WA = W1T + (size_t)e * 524288;
  const bf16* WV = W1T + (size_t)(4 + e) * 524288;

  __shared__ bf16 As[64 * 72];
  __shared__ int rows[64];
  const int tid = threadIdx.x;
  if (tid < 64) {
    int j = m0 + tid; if (j > cntE - 1) j = cntE - 1;
    rows[tid] = perm[e * 4096 + j];
  }
  __syncthreads();

  const int lane = tid & 63, wave = tid >> 6;
  const int lid = lane & 15, c = lane >> 4;
  const int wm = wave >> 2, wn = wave & 3;
  const int srow = tid >> 3, skoff = (tid & 7) * 8;
  const bf16* arow = h3 + (size_t)rows[srow] * 1024 + skoff;
  const int colA = n0 + wn * 32 + lid;
  const bf16* wa0 = WA + (size_t)colA * 1024 + c * 8;
  const bf16* wa1 = WA + (size_t)(colA + 16) * 1024 + c * 8;
  const bf16* wv0 = WV + (size_t)colA * 1024 + c * 8;
  const bf16* wv1 = WV + (size_t)(colA + 16) * 1024 + c * 8;
  const int ar0 = (wm * 32 + lid) * 72 + c * 8;
  const int ar1 = (wm * 32 + 16 + lid) * 72 + c * 8;

  f32x4 acc[2][2][2];
  #pragma unroll
  for (int n = 0; n < 2; ++n)
    #pragma unroll
    for (int m = 0; m < 2; ++m)
      #pragma unroll
      for (int f = 0; f < 2; ++f) acc[n][m][f] = (f32x4){0.f, 0.f, 0.f, 0.f};

  for (int k0 = 0; k0 < 1024; k0 += 64) {
    *(bf16x8*)(&As[srow * 72 + skoff]) = *(const bf16x8*)(arow + k0);
    __syncthreads();
    bf16x8 a[2][2];
    #pragma unroll
    for (int m = 0; m < 2; ++m)
      #pragma unroll
      for (int ks = 0; ks < 2; ++ks)
        a[m][ks] = *(const bf16x8*)(&As[(m ? ar1 : ar0) + ks * 32]);
    #pragma unroll
    for (int ks = 0; ks < 2; ++ks) {
      bf16x8 bA0 = *(const bf16x8*)(wa0 + k0 + ks * 32);
      bf16x8 bA1 = *(const bf16x8*)(wa1 + k0 + ks * 32);
      bf16x8 bV0 = *(const bf16x8*)(wv0 + k0 + ks * 32);
      bf16x8 bV1 = *(const bf16x8*)(wv1 + k0 + ks * 32);
      #pragma unroll
      for (int m = 0; m < 2; ++m) {
        acc[0][m][0] = __builtin_amdgcn_mfma_f32_16x16x32_bf16(a[m][ks], bA0, acc[0][m][0], 0, 0, 0);
        acc[0][m][1] = __builtin_amdgcn_mfma_f32_16x16x32_bf16(a[m][ks], bA1, acc[0][m][1], 0, 0, 0);
        acc[1][m][0] = __builtin_amdgcn_mfma_f32_16x16x32_bf16(a[m][ks], bV0, acc[1][m][0], 0, 0, 0);
        acc[1][m][1] = __builtin_amdgcn_mfma_f32_16x16x32_bf16(a[m][ks], bV1, acc[1][m][1], 0, 0, 0);
      }
    }
    __syncthreads();
  }

  #pragma unroll
  for (int cf = 0; cf < 2; ++cf) {
    const int col = colA + cf * 16;
    const float bA = ab1[e * 512 + col];
    const float bV = vb1[e * 512 + col];
    #pragma unroll
    for (int m = 0; m < 2; ++m)
      #pragma unroll
      for (int r = 0; r < 4; ++r) {
        const int ridx = wm * 32 + m * 16 + c * 4 + r;
        if (m0 + ridx < cntE) {
          const size_t zoff = (size_t)rows[ridx] * 512 + col;
          za[zoff] = (bf16)fmaxf(acc[0][m][cf][r] + bA, 0.f);
          zv[zoff] = (bf16)fmaxf(acc[1][m][cf][r] + bV, 0.f);
        }
      }
  }
}

__global__ __launch_bounds__(256) void k_mlp2(const bf16* __restrict__ za,
    const bf16* __restrict__ zv,
    const float* __restrict__ aW2, const float* __restrict__ ab2,
    const float* __restrict__ vW2, const float* __restrict__ vb2,
    const int* __restrict__ perm, const int* __restrict__ cnt,
    float* __restrict__ out) {
  const int e = blockIdx.y;
  const int cntE = cnt[e];
  const int m0 = blockIdx.x * 64;
  if (m0 >= cntE) return;
  __shared__ bf16 Bs[48 * 520];
  const int tid = threadIdx.x;
  for (int i = tid; i < 512 * 32; i += 256) {
    const int k = i >> 5, n = i & 31;
    Bs[n * 520 + k] = (bf16)aW2[(size_t)e * 16384 + i];
  }
  for (int i = tid; i < 512; i += 256) Bs[32 * 520 + i] = (bf16)vW2[e * 512 + i];
  for (int i = tid; i < 15 * 512; i += 256) {
    const int n = 33 + (i >> 9), k = i & 511;
    Bs[n * 520 + k] = (bf16)0.f;
  }
  __syncthreads();

  const int lane = tid & 63, wave = tid >> 6;
  const int lid = lane & 15, c = lane >> 4;
  const int row0 = m0 + wave * 16;
  if (row0 >= cntE) return;
  int rowl = row0 + lid; if (rowl > cntE - 1) rowl = cntE - 1;
  const int pb = perm[e * 4096 + rowl];
  const bf16* aA = za + (size_t)pb * 512 + c * 8;
  const bf16* aV = zv + (size_t)pb * 512 + c * 8;

  f32x4 acc0 = {0.f, 0.f, 0.f, 0.f}, acc1 = acc0, accv = acc0;
  #pragma unroll
  for (int k0 = 0; k0 < 512; k0 += 32) {
    bf16x8 a1 = *(const bf16x8*)(aA + k0);
    bf16x8 a2 = *(const bf16x8*)(aV + k0);
    bf16x8 b0 = *(const bf16x8*)(&Bs[lid * 520 + k0 + c * 8]);
    bf16x8 b1 = *(const bf16x8*)(&Bs[(16 + lid) * 520 + k0 + c * 8]);
    bf16x8 b2 = *(const bf16x8*)(&Bs[(32 + lid) * 520 + k0 + c * 8]);
    acc0 = __builtin_amdgcn_mfma_f32_16x16x32_bf16(a1, b0, acc0, 0, 0, 0);
    acc1 = __builtin_amdgcn_mfma_f32_16x16x32_bf16(a1, b1, acc1, 0, 0, 0);
    accv = __builtin_amdgcn_mfma_f32_16x16x32_bf16(a2, b2, accv, 0, 0, 0);
  }

  const float ba0 = ab2[e * 32 + lid], ba1 = ab2[e * 32 + 16 + lid], bv = vb2[e];
  #pragma unroll
  for (int r = 0; r < 4; ++r) {
    const int row = row0 + c * 4 + r;
    const float y0 = acc0[r] + ba0, y1 = acc1[r] + ba1;
    float s = y0 + y1;
    s += __shfl_xor(s, 1); s += __shfl_xor(s, 2);
    s += __shfl_xor(s, 4); s += __shfl_xor(s, 8);
    const float mean = s * 0.03125f;
    const float ys = __shfl(accv[r], lane & 48) + bv;
    if (row < cntE) {
      const int bq = perm[e * 4096 + row];
      out[(size_t)bq * 32 + lid] = y0 - mean + ys;
      out[(size_t)bq * 32 + 16 + lid] = y1 - mean + ys;
    }
  }
}

extern "C" void kernel_launch(void* const* d_in, const int* in_sizes, int n_in,
                              void* d_out, int out_size, void* d_ws, size_t ws_size,
                              hipStream_t stream) {
  const float* x   = (const float*)d_in[0];
  const float* cW1 = (const float*)d_in[1];
  const float* cb1 = (const float*)d_in[2];
  const float* cW2 = (const float*)d_in[3];
  const float* cb2 = (const float*)d_in[4];
  const float* cW3 = (const float*)d_in[5];
  const float* cb3 = (const float*)d_in[6];
  const float* aW1 = (const float*)d_in[7];
  const float* ab1 = (const float*)d_in[8];
  const float* aW2 = (const float*)d_in[9];
  const float* ab2 = (const float*)d_in[10];
  const float* vW1 = (const float*)d_in[11];
  const float* vb1 = (const float*)d_in[12];
  const float* vW2 = (const float*)d_in[13];
  const float* vb2 = (const float*)d_in[14];
  const float* bd  = (const float*)d_in[15];
  float* out = (float*)d_out;

  char* ws = (char*)d_ws;
  bf16* W1T = (bf16*)(ws);                          // 8,388,608
  bf16* za  = (bf16*)(ws + 8388608ull);             // 4,194,304
  bf16* zv  = (bf16*)(ws + 12582912ull);            // 4,194,304
  bf16* h3  = (bf16*)(ws + 16777216ull);            // 8,388,608
  bf16* W1p = (bf16*)(ws + 25165824ull);            // 16,384
  bf16* W2p = (bf16*)(ws + 25182208ull);            // 65,536
  bf16* W3p = (bf16*)(ws + 25247744ull);            // 73,728
  int* perm = (int*)(ws + 25321472ull);             // 65,536
  int* cnt  = (int*)(ws + 25387008ull);             // 64
  int* ecls = (int*)(ws + 25387072ull);             // 16,384

  k_pre<<<304, 256, 0, stream>>>(cW1, cW2, cW3, W1p, W2p, W3p);
  k_front<<<5136, 256, 0, stream>>>(x, bd, ecls, aW1, vW1, W1T,
                                    W1p, cb1, W2p, cb2, W3p, cb3, h3);
  k_route_scan<<<1, 1024, 0, stream>>>(ecls, perm, cnt);
  k_mlp1<<<dim3(64, 4, 4), 512, 0, stream>>>(h3, W1T, ab1, vb1, perm, cnt, za, zv);
  k_mlp2<<<dim3(64, 4), 256, 0, stream>>>(za, zv, aW2, ab2, vW2, vb2, perm, cnt, out);
}

// Round 22
// 196.377 us; speedup vs baseline: 1.0572x; 1.0206x over previous
//
#include <hip/hip_runtime.h>
#include <hip/hip_bf16.h>

typedef __bf16 bf16;
typedef bf16 bf16x8 __attribute__((ext_vector_type(8)));
typedef bf16 bf16x4 __attribute__((ext_vector_type(4)));
typedef float f32x4 __attribute__((ext_vector_type(4)));

__device__ __forceinline__ int SZ(int a) { return a ^ (((a >> 7) & 7) << 4); }

__global__ __launch_bounds__(256) void k_pre(const float* __restrict__ cW1,
    const float* __restrict__ cW2, const float* __restrict__ cW3,
    bf16* __restrict__ W1p, bf16* __restrict__ W2p, bf16* __restrict__ W3p) {
  const int bid = blockIdx.x, tid = threadIdx.x;
  if (bid < 32) {
    int i = bid * 256 + tid;            // W1: [oc][ky][kx][ic]
    int oc = i >> 8, k = i & 255;
    int ic = k & 3, kp = k >> 2, kx = kp & 7, ky = kp >> 3;
    W1p[i] = (bf16)cW1[oc * 256 + ic * 64 + ky * 8 + kx];
  } else if (bid < 160) {
    int i = (bid - 32) * 256 + tid;     // W2: [oc][ky][kx][ic]
    int oc = i >> 9, k = i & 511;
    int ic = k & 31, kp = k >> 5, kx = kp & 3, ky = kp >> 2;
    W2p[i] = (bf16)cW2[oc * 512 + ic * 16 + ky * 4 + kx];
  } else {
    int i = (bid - 160) * 256 + tid;    // W3: [oc][ky][kx][ic]
    if (i < 36864) {
      int oc = i / 576, k = i - oc * 576;
      int ic = k & 63, kp = k >> 6, kx = kp % 3, ky = kp / 3;
      W3p[i] = (bf16)cW3[oc * 576 + ic * 9 + ky * 3 + kx];
    }
  }
}

__global__ __launch_bounds__(1024) void k_route_scan(const int* __restrict__ ecls,
    int* __restrict__ perm, int* __restrict__ cnt) {
  const int tid = threadIdx.x;
  const int4 ev = ((const int4*)ecls)[tid];
  int e[4] = {ev.x, ev.y, ev.z, ev.w};
  int lc[4] = {0, 0, 0, 0};
  #pragma unroll
  for (int i = 0; i < 4; ++i) lc[e[i]]++;
  const int lane = tid & 63, wv = tid >> 6;
  __shared__ int wsum[16][4];
  __shared__ int wbase[16][4];
  int pre[4];
  #pragma unroll
  for (int q = 0; q < 4; ++q) {
    int v = lc[q];
    #pragma unroll
    for (int d = 1; d < 64; d <<= 1) {
      int u = __shfl_up(v, d);
      if (lane >= d) v += u;
    }
    pre[q] = v - lc[q];
    if (lane == 63) wsum[wv][q] = v;
  }
  __syncthreads();
  if (tid == 0) {
    int tot[4] = {0, 0, 0, 0};
    for (int w = 0; w < 16; ++w)
      #pragma unroll
      for (int q = 0; q < 4; ++q) { wbase[w][q] = tot[q]; tot[q] += wsum[w][q]; }
    #pragma unroll
    for (int q = 0; q < 4; ++q) cnt[q] = tot[q];
  }
  __syncthreads();
  int run[4];
  #pragma unroll
  for (int q = 0; q < 4; ++q) run[q] = wbase[wv][q] + pre[q];
  #pragma unroll
  for (int i = 0; i < 4; ++i) {
    const int b = tid * 4 + i;
    perm[e[i] * 4096 + run[e[i]]] = b;
    run[e[i]]++;
  }
}

// FUSED FRONT: bid<16 route_cls | bid<1040 W1T transpose | else conv123 (r16 body)
__global__ __launch_bounds__(256, 3) void k_front(const float* __restrict__ x,
    const float* __restrict__ bd, int* __restrict__ ecls,
    const float* __restrict__ aW1, const float* __restrict__ vW1, bf16* __restrict__ W1T,
    const bf16* __restrict__ W1p, const float* __restrict__ b1,
    const bf16* __restrict__ W2p, const float* __restrict__ b2,
    const bf16* __restrict__ W3p, const float* __restrict__ b3,
    bf16* __restrict__ h3) {
  __shared__ bf16 sA[16384];
  __shared__ bf16 sh1[9000];
  const int bid = blockIdx.x, tid = threadIdx.x;

  if (bid < 16) {
    const int b = bid * 256 + tid;
    const float r = x[(size_t)b * 16384 + 12288];
    ecls[b] = (r > bd[0]) + (r > bd[1]) + (r > bd[2]);
    return;
  }
  if (bid < 1040) {
    float* t = (float*)sA;
    const int bid2 = bid - 16;
    const int bz = bid2 >> 7, rest = bid2 & 127, by = rest >> 4, bx = rest & 15;
    const float* in = (bz >= 4 ? vW1 : aW1) + (size_t)(bz & 3) * 524288;
    const int k0 = bx * 64, n0 = by * 64;
    const int cc = tid & 63, r0 = (tid >> 6) * 16;
    for (int i = 0; i < 16; ++i)
      t[(r0 + i) * 65 + cc] = in[(size_t)(k0 + r0 + i) * 512 + n0 + cc];
    __syncthreads();
    for (int i = 0; i < 16; ++i) {
      int n = r0 + i, k = cc;
      W1T[((size_t)bz * 512 + n0 + n) * 1024 + k0 + k] = (bf16)t[k * 65 + n];
    }
    return;
  }

  const int b = bid - 1040;
  const int lane = tid & 63, wave = tid >> 6, lid = lane & 15, c = lane >> 4;

  {
    bf16x8 bw[8];
    const int ot = wave & 1, col = ot * 16 + lid;
    #pragma unroll
    for (int ks = 0; ks < 8; ++ks) bw[ks] = *(const bf16x8*)(W1p + col * 256 + ks * 32 + c * 8);
    const float bias = b1[col];
    #pragma unroll
    for (int ks = 0; ks < 8; ++ks) asm volatile("" : "+v"(bw[ks]));

    const float4* xs = (const float4*)(x + (size_t)b * 16384);
    #pragma unroll
    for (int hb = 0; hb < 2; ++hb) {
      float4 r[2][4];
      #pragma unroll
      for (int h = 0; h < 2; ++h)
        #pragma unroll
        for (int ic = 0; ic < 4; ++ic)
          r[h][ic] = xs[ic * 1024 + tid + (hb * 2 + h) * 256];
      #pragma unroll
      for (int h = 0; h < 2; ++h) {
        const int g = tid + (hb * 2 + h) * 256;
        bf16x8 lo, hi;
        lo[0] = (bf16)r[h][0].x; lo[1] = (bf16)r[h][1].x; lo[2] = (bf16)r[h][2].x; lo[3] = (bf16)r[h][3].x;
        lo[4] = (bf16)r[h][0].y; lo[5] = (bf16)r[h][1].y; lo[6] = (bf16)r[h][2].y; lo[7] = (bf16)r[h][3].y;
        hi[0] = (bf16)r[h][0].z; hi[1] = (bf16)r[h][1].z; hi[2] = (bf16)r[h][2].z; hi[3] = (bf16)r[h][3].z;
        hi[4] = (bf16)r[h][0].w; hi[5] = (bf16)r[h][1].w; hi[6] = (bf16)r[h][2].w; hi[7] = (bf16)r[h][3].w;
        *(bf16x8*)((char*)sA + SZ(g * 32))      = lo;
        *(bf16x8*)((char*)sA + SZ(g * 32 + 16)) = hi;
      }
    }
    __syncthreads();

    int ab[8], ptv[8];
    #pragma unroll
    for (int pi = 0; pi < 8; ++pi) {
      int pt = (wave >> 1) + 2 * pi; if (pt > 14) pt = 14;
      ptv[pi] = pt;
      int p = pt * 16 + lid; if (p > 224) p = 224;
      const int py = p / 15, px = p - py * 15;
      ab[pi] = py * 2048 + px * 32 + c * 16;
    }
    f32x4 acc[8];
    #pragma unroll
    for (int pi = 0; pi < 8; ++pi) acc[pi] = (f32x4){0.f, 0.f, 0.f, 0.f};
    #pragma unroll
    for (int ks = 0; ks < 8; ++ks)
      #pragma unroll
      for (int pi = 0; pi < 8; ++pi)
        acc[pi] = __builtin_amdgcn_mfma_f32_16x16x32_bf16(
            *(const bf16x8*)((const char*)sA + SZ(ab[pi] + ks * 512)), bw[ks], acc[pi], 0, 0, 0);
    __syncthreads();
    #pragma unroll
    for (int pi = 0; pi < 8; ++pi)
      #pragma unroll
      for (int r = 0; r < 4; ++r) {
        const int pr = ptv[pi] * 16 + c * 4 + r;
        if (pr < 225) sh1[pr * 40 + col] = (bf16)fmaxf(acc[pi][r] + bias, 0.f);
      }
  }
  __syncthreads();

  bf16* sh2 = sA;
  const int col = wave * 16 + lid;
  {
    bf16x8 bw2[16];
    #pragma unroll
    for (int ks = 0; ks < 16; ++ks) bw2[ks] = *(const bf16x8*)(W2p + col * 512 + ks * 32 + c * 8);
    const float bias2 = b2[col];
    #pragma unroll
    for (int ks = 0; ks < 16; ++ks) asm volatile("" : "+v"(bw2[ks]));

    int abase[3];
    #pragma unroll
    for (int pt = 0; pt < 3; ++pt) {
      int p = pt * 16 + lid; if (p > 35) p = 35;
      const int oy = p / 6, ox = p - oy * 6;
      abase[pt] = (oy * 30 + ox * 2) * 40 + c * 8;
    }
    f32x4 acc2[3];
    #pragma unroll
    for (int pt = 0; pt < 3; ++pt) acc2[pt] = (f32x4){0.f, 0.f, 0.f, 0.f};
    #pragma unroll
    for (int ks = 0; ks < 16; ++ks) {
      const int ky = ks >> 2, kx = ks & 3;
      #pragma unroll
      for (int pt = 0; pt < 3; ++pt)
        acc2[pt] = __builtin_amdgcn_mfma_f32_16x16x32_bf16(
            *(const bf16x8*)(&sh1[abase[pt] + (ky * 15 + kx) * 40]), bw2[ks], acc2[pt], 0, 0, 0);
    }
    #pragma unroll
    for (int pt = 0; pt < 3; ++pt)
      #pragma unroll
      for (int r = 0; r < 4; ++r) {
        const int pr = pt * 16 + c * 4 + r;
        if (pr < 36) sh2[pr * 72 + col] = (bf16)fmaxf(acc2[pt][r] + bias2, 0.f);
      }
  }
  __syncthreads();

  {
    bf16x8 bw3[18];
    #pragma unroll
    for (int ks = 0; ks < 18; ++ks) bw3[ks] = *(const bf16x8*)(W3p + col * 576 + ks * 32 + c * 8);
    const float bias3 = b3[col];
    #pragma unroll
    for (int ks = 0; ks < 18; ++ks) asm volatile("" : "+v"(bw3[ks]));
    const int oy = lid >> 2, ox = lid & 3;
    const int ab3 = (oy * 6 + ox) * 72 + c * 8;
    f32x4 acc = {0.f, 0.f, 0.f, 0.f};
    #pragma unroll
    for (int ks = 0; ks < 18; ++ks) {
      const int kp = ks >> 1, ky = kp / 3, kx = kp - ky * 3;
      acc = __builtin_amdgcn_mfma_f32_16x16x32_bf16(
          *(const bf16x8*)(&sh2[ab3 + (ky * 6 + kx) * 72 + (ks & 1) * 32]), bw3[ks], acc, 0, 0, 0);
    }
    bf16x4 o;
    #pragma unroll
    for (int r = 0; r < 4; ++r) o[r] = (bf16)fmaxf(acc[r] + bias3, 0.f);
    *(bf16x4*)(h3 + (size_t)b * 1024 + col * 16 + c * 4) = o;
  }
}

// MLP L1 (r21 tiling) + DOUBLE-BUFFERED As: one barrier per K-step, next-tile
// global load + LDS store overlap current MFMAs.
__global__ __launch_bounds__(512) void k_mlp1(const bf16* __restrict__ h3,
    const bf16* __restrict__ W1T, const float* __restrict__ ab1, const float* __restrict__ vb1,
    const int* __restrict__ perm, const int* __restrict__ cnt,
    bf16* __restrict__ za, bf16* __restrict__ zv) {
  const int e = blockIdx.z;
  const int cntE = cnt[e];
  const int m0 = blockIdx.x * 64;
  if (m0 >= cntE) return;
  const int n0 = blockIdx.y * 128;
  const bf16* WA = W1T + (size_t)e * 524288;
  const bf16* WV = W1T + (size_t)(4 + e) * 524288;

  __shared__ bf16 As[2][64 * 72];
  __shared__ int rows[64];
  const int tid = threadIdx.x;
  if (tid < 64) {
    int j = m0 + tid; if (j > cntE - 1) j = cntE - 1;
    rows[tid] = perm[e * 4096 + j];
  }
  __syncthreads();

  const int lane = tid & 63, wave = tid >> 6;
  const int lid = lane & 15, c = lane >> 4;
  const int wm = wave >> 2, wn = wave & 3;
  const int srow = tid >> 3, skoff = (tid & 7) * 8;
  const bf16* arow = h3 + (size_t)rows[srow] * 1024 + skoff;
  const int colA = n0 + wn * 32 + lid;
  const bf16* wa0 = WA + (size_t)colA * 1024 + c * 8;
  const bf16* wa1 = WA + (size_t)(colA + 16) * 1024 + c * 8;
  const bf16* wv0 = WV + (size_t)colA * 1024 + c * 8;
  const bf16* wv1 = WV + (size_t)(colA + 16) * 1024 + c * 8;
  const int ar0 = (wm * 32 + lid) * 72 + c * 8;
  const int ar1 = (wm * 32 + 16 + lid) * 72 + c * 8;
  const int soff = srow * 72 + skoff;

  f32x4 acc[2][2][2];
  #pragma unroll
  for (int n = 0; n < 2; ++n)
    #pragma unroll
    for (int m = 0; m < 2; ++m)
      #pragma unroll
      for (int f = 0; f < 2; ++f) acc[n][m][f] = (f32x4){0.f, 0.f, 0.f, 0.f};

  // prologue: stage K-step 0
  *(bf16x8*)(&As[0][soff]) = *(const bf16x8*)(arow);

  for (int kt = 0; kt < 16; ++kt) {
    const int k0 = kt * 64;
    __syncthreads();   // As[kt&1] ready; prior reads of As[(kt+1)&1] (iter kt-1) done
    if (kt + 1 < 16)
      *(bf16x8*)(&As[(kt + 1) & 1][soff]) = *(const bf16x8*)(arow + k0 + 64);
    const bf16* Ab = As[kt & 1];
    bf16x8 a[2][2];
    #pragma unroll
    for (int m = 0; m < 2; ++m)
      #pragma unroll
      for (int ks = 0; ks < 2; ++ks)
        a[m][ks] = *(const bf16x8*)(&Ab[(m ? ar1 : ar0) + ks * 32]);
    #pragma unroll
    for (int ks = 0; ks < 2; ++ks) {
      bf16x8 bA0 = *(const bf16x8*)(wa0 + k0 + ks * 32);
      bf16x8 bA1 = *(const bf16x8*)(wa1 + k0 + ks * 32);
      bf16x8 bV0 = *(const bf16x8*)(wv0 + k0 + ks * 32);
      bf16x8 bV1 = *(const bf16x8*)(wv1 + k0 + ks * 32);
      #pragma unroll
      for (int m = 0; m < 2; ++m) {
        acc[0][m][0] = __builtin_amdgcn_mfma_f32_16x16x32_bf16(a[m][ks], bA0, acc[0][m][0], 0, 0, 0);
        acc[0][m][1] = __builtin_amdgcn_mfma_f32_16x16x32_bf16(a[m][ks], bA1, acc[0][m][1], 0, 0, 0);
        acc[1][m][0] = __builtin_amdgcn_mfma_f32_16x16x32_bf16(a[m][ks], bV0, acc[1][m][0], 0, 0, 0);
        acc[1][m][1] = __builtin_amdgcn_mfma_f32_16x16x32_bf16(a[m][ks], bV1, acc[1][m][1], 0, 0, 0);
      }
    }
  }

  #pragma unroll
  for (int cf = 0; cf < 2; ++cf) {
    const int col = colA + cf * 16;
    const float bA = ab1[e * 512 + col];
    const float bV = vb1[e * 512 + col];
    #pragma unroll
    for (int m = 0; m < 2; ++m)
      #pragma unroll
      for (int r = 0; r < 4; ++r) {
        const int ridx = wm * 32 + m * 16 + c * 4 + r;
        if (m0 + ridx < cntE) {
          const size_t zoff = (size_t)rows[ridx] * 512 + col;
          za[zoff] = (bf16)fmaxf(acc[0][m][cf][r] + bA, 0.f);
          zv[zoff] = (bf16)fmaxf(acc[1][m][cf][r] + bV, 0.f);
        }
      }
  }
}

__global__ __launch_bounds__(256) void k_mlp2(const bf16* __restrict__ za,
    const bf16* __restrict__ zv,
    const float* __restrict__ aW2, const float* __restrict__ ab2,
    const float* __restrict__ vW2, const float* __restrict__ vb2,
    const int* __restrict__ perm, const int* __restrict__ cnt,
    float* __restrict__ out) {
  const int e = blockIdx.y;
  const int cntE = cnt[e];
  const int m0 = blockIdx.x * 64;
  if (m0 >= cntE) return;
  __shared__ bf16 Bs[48 * 520];
  const int tid = threadIdx.x;
  for (int i = tid; i < 512 * 32; i += 256) {
    const int k = i >> 5, n = i & 31;
    Bs[n * 520 + k] = (bf16)aW2[(size_t)e * 16384 + i];
  }
  for (int i = tid; i < 512; i += 256) Bs[32 * 520 + i] = (bf16)vW2[e * 512 + i];
  for (int i = tid; i < 15 * 512; i += 256) {
    const int n = 33 + (i >> 9), k = i & 511;
    Bs[n * 520 + k] = (bf16)0.f;
  }
  __syncthreads();

  const int lane = tid & 63, wave = tid >> 6;
  const int lid = lane & 15, c = lane >> 4;
  const int row0 = m0 + wave * 16;
  if (row0 >= cntE) return;
  int rowl = row0 + lid; if (rowl > cntE - 1) rowl = cntE - 1;
  const int pb = perm[e * 4096 + rowl];
  const bf16* aA = za + (size_t)pb * 512 + c * 8;
  const bf16* aV = zv + (size_t)pb * 512 + c * 8;

  f32x4 acc0 = {0.f, 0.f, 0.f, 0.f}, acc1 = acc0, accv = acc0;
  #pragma unroll
  for (int k0 = 0; k0 < 512; k0 += 32) {
    bf16x8 a1 = *(const bf16x8*)(aA + k0);
    bf16x8 a2 = *(const bf16x8*)(aV + k0);
    bf16x8 b0 = *(const bf16x8*)(&Bs[lid * 520 + k0 + c * 8]);
    bf16x8 b1 = *(const bf16x8*)(&Bs[(16 + lid) * 520 + k0 + c * 8]);
    bf16x8 b2 = *(const bf16x8*)(&Bs[(32 + lid) * 520 + k0 + c * 8]);
    acc0 = __builtin_amdgcn_mfma_f32_16x16x32_bf16(a1, b0, acc0, 0, 0, 0);
    acc1 = __builtin_amdgcn_mfma_f32_16x16x32_bf16(a1, b1, acc1, 0, 0, 0);
    accv = __builtin_amdgcn_mfma_f32_16x16x32_bf16(a2, b2, accv, 0, 0, 0);
  }

  const float ba0 = ab2[e * 32 + lid], ba1 = ab2[e * 32 + 16 + lid], bv = vb2[e];
  #pragma unroll
  for (int r = 0; r < 4; ++r) {
    const int row = row0 + c * 4 + r;
    const float y0 = acc0[r] + ba0, y1 = acc1[r] + ba1;
    float s = y0 + y1;
    s += __shfl_xor(s, 1); s += __shfl_xor(s, 2);
    s += __shfl_xor(s, 4); s += __shfl_xor(s, 8);
    const float mean = s * 0.03125f;
    const float ys = __shfl(accv[r], lane & 48) + bv;
    if (row < cntE) {
      const int bq = perm[e * 4096 + row];
      out[(size_t)bq * 32 + lid] = y0 - mean + ys;
      out[(size_t)bq * 32 + 16 + lid] = y1 - mean + ys;
    }
  }
}

extern "C" void kernel_launch(void* const* d_in, const int* in_sizes, int n_in,
                              void* d_out, int out_size, void* d_ws, size_t ws_size,
                              hipStream_t stream) {
  const float* x   = (const float*)d_in[0];
  const float* cW1 = (const float*)d_in[1];
  const float* cb1 = (const float*)d_in[2];
  const float* cW2 = (const float*)d_in[3];
  const float* cb2 = (const float*)d_in[4];
  const float* cW3 = (const float*)d_in[5];
  const float* cb3 = (const float*)d_in[6];
  const float* aW1 = (const float*)d_in[7];
  const float* ab1 = (const float*)d_in[8];
  const float* aW2 = (const float*)d_in[9];
  const float* ab2 = (const float*)d_in[10];
  const float* vW1 = (const float*)d_in[11];
  const float* vb1 = (const float*)d_in[12];
  const float* vW2 = (const float*)d_in[13];
  const float* vb2 = (const float*)d_in[14];
  const float* bd  = (const float*)d_in[15];
  float* out = (float*)d_out;

  char* ws = (char*)d_ws;
  bf16* W1T = (bf16*)(ws);                          // 8,388,608
  bf16* za  = (bf16*)(ws + 8388608ull);             // 4,194,304
  bf16* zv  = (bf16*)(ws + 12582912ull);            // 4,194,304
  bf16* h3  = (bf16*)(ws + 16777216ull);            // 8,388,608
  bf16* W1p = (bf16*)(ws + 25165824ull);            // 16,384
  bf16* W2p = (bf16*)(ws + 25182208ull);            // 65,536
  bf16* W3p = (bf16*)(ws + 25247744ull);            // 73,728
  int* perm = (int*)(ws + 25321472ull);             // 65,536
  int* cnt  = (int*)(ws + 25387008ull);             // 64
  int* ecls = (int*)(ws + 25387072ull);             // 16,384

  k_pre<<<304, 256, 0, stream>>>(cW1, cW2, cW3, W1p, W2p, W3p);
  k_front<<<5136, 256, 0, stream>>>(x, bd, ecls, aW1, vW1, W1T,
                                    W1p, cb1, W2p, cb2, W3p, cb3, h3);
  k_route_scan<<<1, 1024, 0, stream>>>(ecls, perm, cnt);
  k_mlp1<<<dim3(64, 4, 4), 512, 0, stream>>>(h3, W1T, ab1, vb1, perm, cnt, za, zv);
  k_mlp2<<<dim3(64, 4), 256, 0, stream>>>(za, zv, aW2, ab2, vW2, vb2, perm, cnt, out);
}

// Round 23
// 194.311 us; speedup vs baseline: 1.0684x; 1.0106x over previous
//
#include <hip/hip_runtime.h>
#include <hip/hip_bf16.h>

typedef __bf16 bf16;
typedef bf16 bf16x8 __attribute__((ext_vector_type(8)));
typedef bf16 bf16x4 __attribute__((ext_vector_type(4)));
typedef float f32x4 __attribute__((ext_vector_type(4)));

__device__ __forceinline__ int SZ(int a) { return a ^ (((a >> 7) & 7) << 4); }

__global__ __launch_bounds__(256) void k_pre(const float* __restrict__ cW1,
    const float* __restrict__ cW2, const float* __restrict__ cW3,
    bf16* __restrict__ W1p, bf16* __restrict__ W2p, bf16* __restrict__ W3p) {
  const int bid = blockIdx.x, tid = threadIdx.x;
  if (bid < 32) {
    int i = bid * 256 + tid;            // W1: [oc][ky][kx][ic]
    int oc = i >> 8, k = i & 255;
    int ic = k & 3, kp = k >> 2, kx = kp & 7, ky = kp >> 3;
    W1p[i] = (bf16)cW1[oc * 256 + ic * 64 + ky * 8 + kx];
  } else if (bid < 160) {
    int i = (bid - 32) * 256 + tid;     // W2: [oc][ky][kx][ic]
    int oc = i >> 9, k = i & 511;
    int ic = k & 31, kp = k >> 5, kx = kp & 3, ky = kp >> 2;
    W2p[i] = (bf16)cW2[oc * 512 + ic * 16 + ky * 4 + kx];
  } else {
    int i = (bid - 160) * 256 + tid;    // W3: [oc][ky][kx][ic]
    if (i < 36864) {
      int oc = i / 576, k = i - oc * 576;
      int ic = k & 63, kp = k >> 6, kx = kp % 3, ky = kp / 3;
      W3p[i] = (bf16)cW3[oc * 576 + ic * 9 + ky * 3 + kx];
    }
  }
}

__global__ __launch_bounds__(1024) void k_route_scan(const int* __restrict__ ecls,
    int* __restrict__ perm, int* __restrict__ cnt) {
  const int tid = threadIdx.x;
  const int4 ev = ((const int4*)ecls)[tid];
  int e[4] = {ev.x, ev.y, ev.z, ev.w};
  int lc[4] = {0, 0, 0, 0};
  #pragma unroll
  for (int i = 0; i < 4; ++i) lc[e[i]]++;
  const int lane = tid & 63, wv = tid >> 6;
  __shared__ int wsum[16][4];
  __shared__ int wbase[16][4];
  int pre[4];
  #pragma unroll
  for (int q = 0; q < 4; ++q) {
    int v = lc[q];
    #pragma unroll
    for (int d = 1; d < 64; d <<= 1) {
      int u = __shfl_up(v, d);
      if (lane >= d) v += u;
    }
    pre[q] = v - lc[q];
    if (lane == 63) wsum[wv][q] = v;
  }
  __syncthreads();
  if (tid == 0) {
    int tot[4] = {0, 0, 0, 0};
    for (int w = 0; w < 16; ++w)
      #pragma unroll
      for (int q = 0; q < 4; ++q) { wbase[w][q] = tot[q]; tot[q] += wsum[w][q]; }
    #pragma unroll
    for (int q = 0; q < 4; ++q) cnt[q] = tot[q];
  }
  __syncthreads();
  int run[4];
  #pragma unroll
  for (int q = 0; q < 4; ++q) run[q] = wbase[wv][q] + pre[q];
  #pragma unroll
  for (int i = 0; i < 4; ++i) {
    const int b = tid * 4 + i;
    perm[e[i] * 4096 + run[e[i]]] = b;
    run[e[i]]++;
  }
}

// FUSED FRONT: bid<16 route_cls | bid<1040 W1T transpose | else conv123.
// Conv: bw2/bw3 loads issued BEFORE the barrier opening their phase (latency
// hides under C-writes + barrier) — same pattern as r22's mlp1 dbuf win.
__global__ __launch_bounds__(256, 3) void k_front(const float* __restrict__ x,
    const float* __restrict__ bd, int* __restrict__ ecls,
    const float* __restrict__ aW1, const float* __restrict__ vW1, bf16* __restrict__ W1T,
    const bf16* __restrict__ W1p, const float* __restrict__ b1,
    const bf16* __restrict__ W2p, const float* __restrict__ b2,
    const bf16* __restrict__ W3p, const float* __restrict__ b3,
    bf16* __restrict__ h3) {
  __shared__ bf16 sA[16384];
  __shared__ bf16 sh1[9000];
  const int bid = blockIdx.x, tid = threadIdx.x;

  if (bid < 16) {
    const int b = bid * 256 + tid;
    const float r = x[(size_t)b * 16384 + 12288];
    ecls[b] = (r > bd[0]) + (r > bd[1]) + (r > bd[2]);
    return;
  }
  if (bid < 1040) {
    float* t = (float*)sA;
    const int bid2 = bid - 16;
    const int bz = bid2 >> 7, rest = bid2 & 127, by = rest >> 4, bx = rest & 15;
    const float* in = (bz >= 4 ? vW1 : aW1) + (size_t)(bz & 3) * 524288;
    const int k0 = bx * 64, n0 = by * 64;
    const int cc = tid & 63, r0 = (tid >> 6) * 16;
    for (int i = 0; i < 16; ++i)
      t[(r0 + i) * 65 + cc] = in[(size_t)(k0 + r0 + i) * 512 + n0 + cc];
    __syncthreads();
    for (int i = 0; i < 16; ++i) {
      int n = r0 + i, k = cc;
      W1T[((size_t)bz * 512 + n0 + n) * 1024 + k0 + k] = (bf16)t[k * 65 + n];
    }
    return;
  }

  const int b = bid - 1040;
  const int lane = tid & 63, wave = tid >> 6, lid = lane & 15, c = lane >> 4;
  const int col = wave * 16 + lid;   // conv2/conv3 column
  bf16x8 bw2[16];
  bf16x8 bw3[18];

  {
    bf16x8 bw[8];
    const int ot = wave & 1, col1 = ot * 16 + lid;
    #pragma unroll
    for (int ks = 0; ks < 8; ++ks) bw[ks] = *(const bf16x8*)(W1p + col1 * 256 + ks * 32 + c * 8);
    const float bias = b1[col1];
    #pragma unroll
    for (int ks = 0; ks < 8; ++ks) asm volatile("" : "+v"(bw[ks]));

    const float4* xs = (const float4*)(x + (size_t)b * 16384);
    #pragma unroll
    for (int hb = 0; hb < 2; ++hb) {
      float4 r[2][4];
      #pragma unroll
      for (int h = 0; h < 2; ++h)
        #pragma unroll
        for (int ic = 0; ic < 4; ++ic)
          r[h][ic] = xs[ic * 1024 + tid + (hb * 2 + h) * 256];
      #pragma unroll
      for (int h = 0; h < 2; ++h) {
        const int g = tid + (hb * 2 + h) * 256;
        bf16x8 lo, hi;
        lo[0] = (bf16)r[h][0].x; lo[1] = (bf16)r[h][1].x; lo[2] = (bf16)r[h][2].x; lo[3] = (bf16)r[h][3].x;
        lo[4] = (bf16)r[h][0].y; lo[5] = (bf16)r[h][1].y; lo[6] = (bf16)r[h][2].y; lo[7] = (bf16)r[h][3].y;
        hi[0] = (bf16)r[h][0].z; hi[1] = (bf16)r[h][1].z; hi[2] = (bf16)r[h][2].z; hi[3] = (bf16)r[h][3].z;
        hi[4] = (bf16)r[h][0].w; hi[5] = (bf16)r[h][1].w; hi[6] = (bf16)r[h][2].w; hi[7] = (bf16)r[h][3].w;
        *(bf16x8*)((char*)sA + SZ(g * 32))      = lo;
        *(bf16x8*)((char*)sA + SZ(g * 32 + 16)) = hi;
      }
    }
    __syncthreads();

    int ab[8], ptv[8];
    #pragma unroll
    for (int pi = 0; pi < 8; ++pi) {
      int pt = (wave >> 1) + 2 * pi; if (pt > 14) pt = 14;
      ptv[pi] = pt;
      int p = pt * 16 + lid; if (p > 224) p = 224;
      const int py = p / 15, px = p - py * 15;
      ab[pi] = py * 2048 + px * 32 + c * 16;
    }
    f32x4 acc[8];
    #pragma unroll
    for (int pi = 0; pi < 8; ++pi) acc[pi] = (f32x4){0.f, 0.f, 0.f, 0.f};
    #pragma unroll
    for (int ks = 0; ks < 8; ++ks)
      #pragma unroll
      for (int pi = 0; pi < 8; ++pi)
        acc[pi] = __builtin_amdgcn_mfma_f32_16x16x32_bf16(
            *(const bf16x8*)((const char*)sA + SZ(ab[pi] + ks * 512)), bw[ks], acc[pi], 0, 0, 0);

    // hoist conv2 weight loads: latency hides under sh1 writes + 2 barriers
    #pragma unroll
    for (int ks = 0; ks < 16; ++ks) bw2[ks] = *(const bf16x8*)(W2p + col * 512 + ks * 32 + c * 8);

    __syncthreads();
    #pragma unroll
    for (int pi = 0; pi < 8; ++pi)
      #pragma unroll
      for (int r = 0; r < 4; ++r) {
        const int pr = ptv[pi] * 16 + c * 4 + r;
        if (pr < 225) sh1[pr * 40 + col1] = (bf16)fmaxf(acc[pi][r] + bias, 0.f);
      }
  }
  __syncthreads();

  bf16* sh2 = sA;
  {
    const float bias2 = b2[col];
    int abase[3];
    #pragma unroll
    for (int pt = 0; pt < 3; ++pt) {
      int p = pt * 16 + lid; if (p > 35) p = 35;
      const int oy = p / 6, ox = p - oy * 6;
      abase[pt] = (oy * 30 + ox * 2) * 40 + c * 8;
    }
    f32x4 acc2[3];
    #pragma unroll
    for (int pt = 0; pt < 3; ++pt) acc2[pt] = (f32x4){0.f, 0.f, 0.f, 0.f};
    #pragma unroll
    for (int ks = 0; ks < 16; ++ks) {
      const int ky = ks >> 2, kx = ks & 3;
      #pragma unroll
      for (int pt = 0; pt < 3; ++pt)
        acc2[pt] = __builtin_amdgcn_mfma_f32_16x16x32_bf16(
            *(const bf16x8*)(&sh1[abase[pt] + (ky * 15 + kx) * 40]), bw2[ks], acc2[pt], 0, 0, 0);
    }

    // hoist conv3 weight loads: latency hides under sh2 writes + barrier
    #pragma unroll
    for (int ks = 0; ks < 18; ++ks) bw3[ks] = *(const bf16x8*)(W3p + col * 576 + ks * 32 + c * 8);

    #pragma unroll
    for (int pt = 0; pt < 3; ++pt)
      #pragma unroll
      for (int r = 0; r < 4; ++r) {
        const int pr = pt * 16 + c * 4 + r;
        if (pr < 36) sh2[pr * 72 + col] = (bf16)fmaxf(acc2[pt][r] + bias2, 0.f);
      }
  }
  __syncthreads();

  {
    const float bias3 = b3[col];
    const int oy = lid >> 2, ox = lid & 3;
    const int ab3 = (oy * 6 + ox) * 72 + c * 8;
    f32x4 acc = {0.f, 0.f, 0.f, 0.f};
    #pragma unroll
    for (int ks = 0; ks < 18; ++ks) {
      const int kp = ks >> 1, ky = kp / 3, kx = kp - ky * 3;
      acc = __builtin_amdgcn_mfma_f32_16x16x32_bf16(
          *(const bf16x8*)(&sh2[ab3 + (ky * 6 + kx) * 72 + (ks & 1) * 32]), bw3[ks], acc, 0, 0, 0);
    }
    bf16x4 o;
    #pragma unroll
    for (int r = 0; r < 4; ++r) o[r] = (bf16)fmaxf(acc[r] + bias3, 0.f);
    *(bf16x4*)(h3 + (size_t)b * 1024 + col * 16 + c * 4) = o;
  }
}

// MLP L1 (r21 tiling) + double-buffered As (r22 win)
__global__ __launch_bounds__(512) void k_mlp1(const bf16* __restrict__ h3,
    const bf16* __restrict__ W1T, const float* __restrict__ ab1, const float* __restrict__ vb1,
    const int* __restrict__ perm, const int* __restrict__ cnt,
    bf16* __restrict__ za, bf16* __restrict__ zv) {
  const int e = blockIdx.z;
  const int cntE = cnt[e];
  const int m0 = blockIdx.x * 64;
  if (m0 >= cntE) return;
  const int n0 = blockIdx.y * 128;
  const bf16* WA = W1T + (size_t)e * 524288;
  const bf16* WV = W1T + (size_t)(4 + e) * 524288;

  __shared__ bf16 As[2][64 * 72];
  __shared__ int rows[64];
  const int tid = threadIdx.x;
  if (tid < 64) {
    int j = m0 + tid; if (j > cntE - 1) j = cntE - 1;
    rows[tid] = perm[e * 4096 + j];
  }
  __syncthreads();

  const int lane = tid & 63, wave = tid >> 6;
  const int lid = lane & 15, c = lane >> 4;
  const int wm = wave >> 2, wn = wave & 3;
  const int srow = tid >> 3, skoff = (tid & 7) * 8;
  const bf16* arow = h3 + (size_t)rows[srow] * 1024 + skoff;
  const int colA = n0 + wn * 32 + lid;
  const bf16* wa0 = WA + (size_t)colA * 1024 + c * 8;
  const bf16* wa1 = WA + (size_t)(colA + 16) * 1024 + c * 8;
  const bf16* wv0 = WV + (size_t)colA * 1024 + c * 8;
  const bf16* wv1 = WV + (size_t)(colA + 16) * 1024 + c * 8;
  const int ar0 = (wm * 32 + lid) * 72 + c * 8;
  const int ar1 = (wm * 32 + 16 + lid) * 72 + c * 8;
  const int soff = srow * 72 + skoff;

  f32x4 acc[2][2][2];
  #pragma unroll
  for (int n = 0; n < 2; ++n)
    #pragma unroll
    for (int m = 0; m < 2; ++m)
      #pragma unroll
      for (int f = 0; f < 2; ++f) acc[n][m][f] = (f32x4){0.f, 0.f, 0.f, 0.f};

  *(bf16x8*)(&As[0][soff]) = *(const bf16x8*)(arow);

  for (int kt = 0; kt < 16; ++kt) {
    const int k0 = kt * 64;
    __syncthreads();
    if (kt + 1 < 16)
      *(bf16x8*)(&As[(kt + 1) & 1][soff]) = *(const bf16x8*)(arow + k0 + 64);
    const bf16* Ab = As[kt & 1];
    bf16x8 a[2][2];
    #pragma unroll
    for (int m = 0; m < 2; ++m)
      #pragma unroll
      for (int ks = 0; ks < 2; ++ks)
        a[m][ks] = *(const bf16x8*)(&Ab[(m ? ar1 : ar0) + ks * 32]);
    #pragma unroll
    for (int ks = 0; ks < 2; ++ks) {
      bf16x8 bA0 = *(const bf16x8*)(wa0 + k0 + ks * 32);
      bf16x8 bA1 = *(const bf16x8*)(wa1 + k0 + ks * 32);
      bf16x8 bV0 = *(const bf16x8*)(wv0 + k0 + ks * 32);
      bf16x8 bV1 = *(const bf16x8*)(wv1 + k0 + ks * 32);
      #pragma unroll
      for (int m = 0; m < 2; ++m) {
        acc[0][m][0] = __builtin_amdgcn_mfma_f32_16x16x32_bf16(a[m][ks], bA0, acc[0][m][0], 0, 0, 0);
        acc[0][m][1] = __builtin_amdgcn_mfma_f32_16x16x32_bf16(a[m][ks], bA1, acc[0][m][1], 0, 0, 0);
        acc[1][m][0] = __builtin_amdgcn_mfma_f32_16x16x32_bf16(a[m][ks], bV0, acc[1][m][0], 0, 0, 0);
        acc[1][m][1] = __builtin_amdgcn_mfma_f32_16x16x32_bf16(a[m][ks], bV1, acc[1][m][1], 0, 0, 0);
      }
    }
  }

  #pragma unroll
  for (int cf = 0; cf < 2; ++cf) {
    const int col = colA + cf * 16;
    const float bA = ab1[e * 512 + col];
    const float bV = vb1[e * 512 + col];
    #pragma unroll
    for (int m = 0; m < 2; ++m)
      #pragma unroll
      for (int r = 0; r < 4; ++r) {
        const int ridx = wm * 32 + m * 16 + c * 4 + r;
        if (m0 + ridx < cntE) {
          const size_t zoff = (size_t)rows[ridx] * 512 + col;
          za[zoff] = (bf16)fmaxf(acc[0][m][cf][r] + bA, 0.f);
          zv[zoff] = (bf16)fmaxf(acc[1][m][cf][r] + bV, 0.f);
        }
      }
  }
}

__global__ __launch_bounds__(256) void k_mlp2(const bf16* __restrict__ za,
    const bf16* __restrict__ zv,
    const float* __restrict__ aW2, const float* __restrict__ ab2,
    const float* __restrict__ vW2, const float* __restrict__ vb2,
    const int* __restrict__ perm, const int* __restrict__ cnt,
    float* __restrict__ out) {
  const int e = blockIdx.y;
  const int cntE = cnt[e];
  const int m0 = blockIdx.x * 64;
  if (m0 >= cntE) return;
  __shared__ bf16 Bs[48 * 520];
  const int tid = threadIdx.x;
  for (int i = tid; i < 512 * 32; i += 256) {
    const int k = i >> 5, n = i & 31;
    Bs[n * 520 + k] = (bf16)aW2[(size_t)e * 16384 + i];
  }
  for (int i = tid; i < 512; i += 256) Bs[32 * 520 + i] = (bf16)vW2[e * 512 + i];
  for (int i = tid; i < 15 * 512; i += 256) {
    const int n = 33 + (i >> 9), k = i & 511;
    Bs[n * 520 + k] = (bf16)0.f;
  }
  __syncthreads();

  const int lane = tid & 63, wave = tid >> 6;
  const int lid = lane & 15, c = lane >> 4;
  const int row0 = m0 + wave * 16;
  if (row0 >= cntE) return;
  int rowl = row0 + lid; if (rowl > cntE - 1) rowl = cntE - 1;
  const int pb = perm[e * 4096 + rowl];
  const bf16* aA = za + (size_t)pb * 512 + c * 8;
  const bf16* aV = zv + (size_t)pb * 512 + c * 8;

  f32x4 acc0 = {0.f, 0.f, 0.f, 0.f}, acc1 = acc0, accv = acc0;
  #pragma unroll
  for (int k0 = 0; k0 < 512; k0 += 32) {
    bf16x8 a1 = *(const bf16x8*)(aA + k0);
    bf16x8 a2 = *(const bf16x8*)(aV + k0);
    bf16x8 b0 = *(const bf16x8*)(&Bs[lid * 520 + k0 + c * 8]);
    bf16x8 b1 = *(const bf16x8*)(&Bs[(16 + lid) * 520 + k0 + c * 8]);
    bf16x8 b2 = *(const bf16x8*)(&Bs[(32 + lid) * 520 + k0 + c * 8]);
    acc0 = __builtin_amdgcn_mfma_f32_16x16x32_bf16(a1, b0, acc0, 0, 0, 0);
    acc1 = __builtin_amdgcn_mfma_f32_16x16x32_bf16(a1, b1, acc1, 0, 0, 0);
    accv = __builtin_amdgcn_mfma_f32_16x16x32_bf16(a2, b2, accv, 0, 0, 0);
  }

  const float ba0 = ab2[e * 32 + lid], ba1 = ab2[e * 32 + 16 + lid], bv = vb2[e];
  #pragma unroll
  for (int r = 0; r < 4; ++r) {
    const int row = row0 + c * 4 + r;
    const float y0 = acc0[r] + ba0, y1 = acc1[r] + ba1;
    float s = y0 + y1;
    s += __shfl_xor(s, 1); s += __shfl_xor(s, 2);
    s += __shfl_xor(s, 4); s += __shfl_xor(s, 8);
    const float mean = s * 0.03125f;
    const float ys = __shfl(accv[r], lane & 48) + bv;
    if (row < cntE) {
      const int bq = perm[e * 4096 + row];
      out[(size_t)bq * 32 + lid] = y0 - mean + ys;
      out[(size_t)bq * 32 + 16 + lid] = y1 - mean + ys;
    }
  }
}

extern "C" void kernel_launch(void* const* d_in, const int* in_sizes, int n_in,
                              void* d_out, int out_size, void* d_ws, size_t ws_size,
                              hipStream_t stream) {
  const float* x   = (const float*)d_in[0];
  const float* cW1 = (const float*)d_in[1];
  const float* cb1 = (const float*)d_in[2];
  const float* cW2 = (const float*)d_in[3];
  const float* cb2 = (const float*)d_in[4];
  const float* cW3 = (const float*)d_in[5];
  const float* cb3 = (const float*)d_in[6];
  const float* aW1 = (const float*)d_in[7];
  const float* ab1 = (const float*)d_in[8];
  const float* aW2 = (const float*)d_in[9];
  const float* ab2 = (const float*)d_in[10];
  const float* vW1 = (const float*)d_in[11];
  const float* vb1 = (const float*)d_in[12];
  const float* vW2 = (const float*)d_in[13];
  const float* vb2 = (const float*)d_in[14];
  const float* bd  = (const float*)d_in[15];
  float* out = (float*)d_out;

  char* ws = (char*)d_ws;
  bf16* W1T = (bf16*)(ws);                          // 8,388,608
  bf16* za  = (bf16*)(ws + 8388608ull);             // 4,194,304
  bf16* zv  = (bf16*)(ws + 12582912ull);            // 4,194,304
  bf16* h3  = (bf16*)(ws + 16777216ull);            // 8,388,608
  bf16* W1p = (bf16*)(ws + 25165824ull);            // 16,384
  bf16* W2p = (bf16*)(ws + 25182208ull);            // 65,536
  bf16* W3p = (bf16*)(ws + 25247744ull);            // 73,728
  int* perm = (int*)(ws + 25321472ull);             // 65,536
  int* cnt  = (int*)(ws + 25387008ull);             // 64
  int* ecls = (int*)(ws + 25387072ull);             // 16,384

  k_pre<<<304, 256, 0, stream>>>(cW1, cW2, cW3, W1p, W2p, W3p);
  k_front<<<5136, 256, 0, stream>>>(x, bd, ecls, aW1, vW1, W1T,
                                    W1p, cb1, W2p, cb2, W3p, cb3, h3);
  k_route_scan<<<1, 1024, 0, stream>>>(ecls, perm, cnt);
  k_mlp1<<<dim3(64, 4, 4), 512, 0, stream>>>(h3, W1T, ab1, vb1, perm, cnt, za, zv);
  k_mlp2<<<dim3(64, 4), 256, 0, stream>>>(za, zv, aW2, ab2, vW2, vb2, perm, cnt, out);
}

// Round 24
// 193.737 us; speedup vs baseline: 1.0716x; 1.0030x over previous
//
#include <hip/hip_runtime.h>
#include <hip/hip_bf16.h>

typedef __bf16 bf16;
typedef bf16 bf16x8 __attribute__((ext_vector_type(8)));
typedef bf16 bf16x4 __attribute__((ext_vector_type(4)));
typedef float f32x4 __attribute__((ext_vector_type(4)));

__device__ __forceinline__ int SZ(int a) { return a ^ (((a >> 7) & 7) << 4); }

__global__ __launch_bounds__(256) void k_pre(const float* __restrict__ cW1,
    const float* __restrict__ cW2, const float* __restrict__ cW3,
    bf16* __restrict__ W1p, bf16* __restrict__ W2p, bf16* __restrict__ W3p) {
  const int bid = blockIdx.x, tid = threadIdx.x;
  if (bid < 32) {
    int i = bid * 256 + tid;            // W1: [oc][ky][kx][ic]
    int oc = i >> 8, k = i & 255;
    int ic = k & 3, kp = k >> 2, kx = kp & 7, ky = kp >> 3;
    W1p[i] = (bf16)cW1[oc * 256 + ic * 64 + ky * 8 + kx];
  } else if (bid < 160) {
    int i = (bid - 32) * 256 + tid;     // W2: [oc][ky][kx][ic]
    int oc = i >> 9, k = i & 511;
    int ic = k & 31, kp = k >> 5, kx = kp & 3, ky = kp >> 2;
    W2p[i] = (bf16)cW2[oc * 512 + ic * 16 + ky * 4 + kx];
  } else {
    int i = (bid - 160) * 256 + tid;    // W3: [oc][ky][kx][ic]
    if (i < 36864) {
      int oc = i / 576, k = i - oc * 576;
      int ic = k & 63, kp = k >> 6, kx = kp % 3, ky = kp / 3;
      W3p[i] = (bf16)cW3[oc * 576 + ic * 9 + ky * 3 + kx];
    }
  }
}

__global__ __launch_bounds__(1024) void k_route_scan(const int* __restrict__ ecls,
    int* __restrict__ perm, int* __restrict__ cnt) {
  const int tid = threadIdx.x;
  const int4 ev = ((const int4*)ecls)[tid];
  int e[4] = {ev.x, ev.y, ev.z, ev.w};
  int lc[4] = {0, 0, 0, 0};
  #pragma unroll
  for (int i = 0; i < 4; ++i) lc[e[i]]++;
  const int lane = tid & 63, wv = tid >> 6;
  __shared__ int wsum[16][4];
  __shared__ int wbase[16][4];
  int pre[4];
  #pragma unroll
  for (int q = 0; q < 4; ++q) {
    int v = lc[q];
    #pragma unroll
    for (int d = 1; d < 64; d <<= 1) {
      int u = __shfl_up(v, d);
      if (lane >= d) v += u;
    }
    pre[q] = v - lc[q];
    if (lane == 63) wsum[wv][q] = v;
  }
  __syncthreads();
  if (tid == 0) {
    int tot[4] = {0, 0, 0, 0};
    for (int w = 0; w < 16; ++w)
      #pragma unroll
      for (int q = 0; q < 4; ++q) { wbase[w][q] = tot[q]; tot[q] += wsum[w][q]; }
    #pragma unroll
    for (int q = 0; q < 4; ++q) cnt[q] = tot[q];
  }
  __syncthreads();
  int run[4];
  #pragma unroll
  for (int q = 0; q < 4; ++q) run[q] = wbase[wv][q] + pre[q];
  #pragma unroll
  for (int i = 0; i < 4; ++i) {
    const int b = tid * 4 + i;
    perm[e[i] * 4096 + run[e[i]]] = b;
    run[e[i]]++;
  }
}

// FUSED FRONT: bid<16 route_cls | bid<1040 W1T transpose | else conv123.
// r23 + s_setprio(1) around MFMA clusters (independent blocks at staggered
// phases: the regime where setprio pays).
__global__ __launch_bounds__(256, 3) void k_front(const float* __restrict__ x,
    const float* __restrict__ bd, int* __restrict__ ecls,
    const float* __restrict__ aW1, const float* __restrict__ vW1, bf16* __restrict__ W1T,
    const bf16* __restrict__ W1p, const float* __restrict__ b1,
    const bf16* __restrict__ W2p, const float* __restrict__ b2,
    const bf16* __restrict__ W3p, const float* __restrict__ b3,
    bf16* __restrict__ h3) {
  __shared__ bf16 sA[16384];
  __shared__ bf16 sh1[9000];
  const int bid = blockIdx.x, tid = threadIdx.x;

  if (bid < 16) {
    const int b = bid * 256 + tid;
    const float r = x[(size_t)b * 16384 + 12288];
    ecls[b] = (r > bd[0]) + (r > bd[1]) + (r > bd[2]);
    return;
  }
  if (bid < 1040) {
    float* t = (float*)sA;
    const int bid2 = bid - 16;
    const int bz = bid2 >> 7, rest = bid2 & 127, by = rest >> 4, bx = rest & 15;
    const float* in = (bz >= 4 ? vW1 : aW1) + (size_t)(bz & 3) * 524288;
    const int k0 = bx * 64, n0 = by * 64;
    const int cc = tid & 63, r0 = (tid >> 6) * 16;
    for (int i = 0; i < 16; ++i)
      t[(r0 + i) * 65 + cc] = in[(size_t)(k0 + r0 + i) * 512 + n0 + cc];
    __syncthreads();
    for (int i = 0; i < 16; ++i) {
      int n = r0 + i, k = cc;
      W1T[((size_t)bz * 512 + n0 + n) * 1024 + k0 + k] = (bf16)t[k * 65 + n];
    }
    return;
  }

  const int b = bid - 1040;
  const int lane = tid & 63, wave = tid >> 6, lid = lane & 15, c = lane >> 4;
  const int col = wave * 16 + lid;   // conv2/conv3 column
  bf16x8 bw2[16];
  bf16x8 bw3[18];

  {
    bf16x8 bw[8];
    const int ot = wave & 1, col1 = ot * 16 + lid;
    #pragma unroll
    for (int ks = 0; ks < 8; ++ks) bw[ks] = *(const bf16x8*)(W1p + col1 * 256 + ks * 32 + c * 8);
    const float bias = b1[col1];
    #pragma unroll
    for (int ks = 0; ks < 8; ++ks) asm volatile("" : "+v"(bw[ks]));

    const float4* xs = (const float4*)(x + (size_t)b * 16384);
    #pragma unroll
    for (int hb = 0; hb < 2; ++hb) {
      float4 r[2][4];
      #pragma unroll
      for (int h = 0; h < 2; ++h)
        #pragma unroll
        for (int ic = 0; ic < 4; ++ic)
          r[h][ic] = xs[ic * 1024 + tid + (hb * 2 + h) * 256];
      #pragma unroll
      for (int h = 0; h < 2; ++h) {
        const int g = tid + (hb * 2 + h) * 256;
        bf16x8 lo, hi;
        lo[0] = (bf16)r[h][0].x; lo[1] = (bf16)r[h][1].x; lo[2] = (bf16)r[h][2].x; lo[3] = (bf16)r[h][3].x;
        lo[4] = (bf16)r[h][0].y; lo[5] = (bf16)r[h][1].y; lo[6] = (bf16)r[h][2].y; lo[7] = (bf16)r[h][3].y;
        hi[0] = (bf16)r[h][0].z; hi[1] = (bf16)r[h][1].z; hi[2] = (bf16)r[h][2].z; hi[3] = (bf16)r[h][3].z;
        hi[4] = (bf16)r[h][0].w; hi[5] = (bf16)r[h][1].w; hi[6] = (bf16)r[h][2].w; hi[7] = (bf16)r[h][3].w;
        *(bf16x8*)((char*)sA + SZ(g * 32))      = lo;
        *(bf16x8*)((char*)sA + SZ(g * 32 + 16)) = hi;
      }
    }
    __syncthreads();

    int ab[8], ptv[8];
    #pragma unroll
    for (int pi = 0; pi < 8; ++pi) {
      int pt = (wave >> 1) + 2 * pi; if (pt > 14) pt = 14;
      ptv[pi] = pt;
      int p = pt * 16 + lid; if (p > 224) p = 224;
      const int py = p / 15, px = p - py * 15;
      ab[pi] = py * 2048 + px * 32 + c * 16;
    }
    f32x4 acc[8];
    #pragma unroll
    for (int pi = 0; pi < 8; ++pi) acc[pi] = (f32x4){0.f, 0.f, 0.f, 0.f};
    __builtin_amdgcn_s_setprio(1);
    #pragma unroll
    for (int ks = 0; ks < 8; ++ks)
      #pragma unroll
      for (int pi = 0; pi < 8; ++pi)
        acc[pi] = __builtin_amdgcn_mfma_f32_16x16x32_bf16(
            *(const bf16x8*)((const char*)sA + SZ(ab[pi] + ks * 512)), bw[ks], acc[pi], 0, 0, 0);
    __builtin_amdgcn_s_setprio(0);

    // hoist conv2 weight loads: latency hides under sh1 writes + 2 barriers
    #pragma unroll
    for (int ks = 0; ks < 16; ++ks) bw2[ks] = *(const bf16x8*)(W2p + col * 512 + ks * 32 + c * 8);

    __syncthreads();
    #pragma unroll
    for (int pi = 0; pi < 8; ++pi)
      #pragma unroll
      for (int r = 0; r < 4; ++r) {
        const int pr = ptv[pi] * 16 + c * 4 + r;
        if (pr < 225) sh1[pr * 40 + col1] = (bf16)fmaxf(acc[pi][r] + bias, 0.f);
      }
  }
  __syncthreads();

  bf16* sh2 = sA;
  {
    const float bias2 = b2[col];
    int abase[3];
    #pragma unroll
    for (int pt = 0; pt < 3; ++pt) {
      int p = pt * 16 + lid; if (p > 35) p = 35;
      const int oy = p / 6, ox = p - oy * 6;
      abase[pt] = (oy * 30 + ox * 2) * 40 + c * 8;
    }
    f32x4 acc2[3];
    #pragma unroll
    for (int pt = 0; pt < 3; ++pt) acc2[pt] = (f32x4){0.f, 0.f, 0.f, 0.f};
    __builtin_amdgcn_s_setprio(1);
    #pragma unroll
    for (int ks = 0; ks < 16; ++ks) {
      const int ky = ks >> 2, kx = ks & 3;
      #pragma unroll
      for (int pt = 0; pt < 3; ++pt)
        acc2[pt] = __builtin_amdgcn_mfma_f32_16x16x32_bf16(
            *(const bf16x8*)(&sh1[abase[pt] + (ky * 15 + kx) * 40]), bw2[ks], acc2[pt], 0, 0, 0);
    }
    __builtin_amdgcn_s_setprio(0);

    // hoist conv3 weight loads: latency hides under sh2 writes + barrier
    #pragma unroll
    for (int ks = 0; ks < 18; ++ks) bw3[ks] = *(const bf16x8*)(W3p + col * 576 + ks * 32 + c * 8);

    #pragma unroll
    for (int pt = 0; pt < 3; ++pt)
      #pragma unroll
      for (int r = 0; r < 4; ++r) {
        const int pr = pt * 16 + c * 4 + r;
        if (pr < 36) sh2[pr * 72 + col] = (bf16)fmaxf(acc2[pt][r] + bias2, 0.f);
      }
  }
  __syncthreads();

  {
    const float bias3 = b3[col];
    const int oy = lid >> 2, ox = lid & 3;
    const int ab3 = (oy * 6 + ox) * 72 + c * 8;
    f32x4 acc = {0.f, 0.f, 0.f, 0.f};
    __builtin_amdgcn_s_setprio(1);
    #pragma unroll
    for (int ks = 0; ks < 18; ++ks) {
      const int kp = ks >> 1, ky = kp / 3, kx = kp - ky * 3;
      acc = __builtin_amdgcn_mfma_f32_16x16x32_bf16(
          *(const bf16x8*)(&sh2[ab3 + (ky * 6 + kx) * 72 + (ks & 1) * 32]), bw3[ks], acc, 0, 0, 0);
    }
    __builtin_amdgcn_s_setprio(0);
    bf16x4 o;
    #pragma unroll
    for (int r = 0; r < 4; ++r) o[r] = (bf16)fmaxf(acc[r] + bias3, 0.f);
    *(bf16x4*)(h3 + (size_t)b * 1024 + col * 16 + c * 4) = o;
  }
}

// MLP L1 (r21 tiling) + double-buffered As (r22) + setprio around MFMA cluster
__global__ __launch_bounds__(512) void k_mlp1(const bf16* __restrict__ h3,
    const bf16* __restrict__ W1T, const float* __restrict__ ab1, const float* __restrict__ vb1,
    const int* __restrict__ perm, const int* __restrict__ cnt,
    bf16* __restrict__ za, bf16* __restrict__ zv) {
  const int e = blockIdx.z;
  const int cntE = cnt[e];
  const int m0 = blockIdx.x * 64;
  if (m0 >= cntE) return;
  const int n0 = blockIdx.y * 128;
  const bf16* WA = W1T + (size_t)e * 524288;
  const bf16* WV = W1T + (size_t)(4 + e) * 524288;

  __shared__ bf16 As[2][64 * 72];
  __shared__ int rows[64];
  const int tid = threadIdx.x;
  if (tid < 64) {
    int j = m0 + tid; if (j > cntE - 1) j = cntE - 1;
    rows[tid] = perm[e * 4096 + j];
  }
  __syncthreads();

  const int lane = tid & 63, wave = tid >> 6;
  const int lid = lane & 15, c = lane >> 4;
  const int wm = wave >> 2, wn = wave & 3;
  const int srow = tid >> 3, skoff = (tid & 7) * 8;
  const bf16* arow = h3 + (size_t)rows[srow] * 1024 + skoff;
  const int colA = n0 + wn * 32 + lid;
  const bf16* wa0 = WA + (size_t)colA * 1024 + c * 8;
  const bf16* wa1 = WA + (size_t)(colA + 16) * 1024 + c * 8;
  const bf16* wv0 = WV + (size_t)colA * 1024 + c * 8;
  const bf16* wv1 = WV + (size_t)(colA + 16) * 1024 + c * 8;
  const int ar0 = (wm * 32 + lid) * 72 + c * 8;
  const int ar1 = (wm * 32 + 16 + lid) * 72 + c * 8;
  const int soff = srow * 72 + skoff;

  f32x4 acc[2][2][2];
  #pragma unroll
  for (int n = 0; n < 2; ++n)
    #pragma unroll
    for (int m = 0; m < 2; ++m)
      #pragma unroll
      for (int f = 0; f < 2; ++f) acc[n][m][f] = (f32x4){0.f, 0.f, 0.f, 0.f};

  *(bf16x8*)(&As[0][soff]) = *(const bf16x8*)(arow);

  for (int kt = 0; kt < 16; ++kt) {
    const int k0 = kt * 64;
    __syncthreads();
    if (kt + 1 < 16)
      *(bf16x8*)(&As[(kt + 1) & 1][soff]) = *(const bf16x8*)(arow + k0 + 64);
    const bf16* Ab = As[kt & 1];
    bf16x8 a[2][2];
    #pragma unroll
    for (int m = 0; m < 2; ++m)
      #pragma unroll
      for (int ks = 0; ks < 2; ++ks)
        a[m][ks] = *(const bf16x8*)(&Ab[(m ? ar1 : ar0) + ks * 32]);
    __builtin_amdgcn_s_setprio(1);
    #pragma unroll
    for (int ks = 0; ks < 2; ++ks) {
      bf16x8 bA0 = *(const bf16x8*)(wa0 + k0 + ks * 32);
      bf16x8 bA1 = *(const bf16x8*)(wa1 + k0 + ks * 32);
      bf16x8 bV0 = *(const bf16x8*)(wv0 + k0 + ks * 32);
      bf16x8 bV1 = *(const bf16x8*)(wv1 + k0 + ks * 32);
      #pragma unroll
      for (int m = 0; m < 2; ++m) {
        acc[0][m][0] = __builtin_amdgcn_mfma_f32_16x16x32_bf16(a[m][ks], bA0, acc[0][m][0], 0, 0, 0);
        acc[0][m][1] = __builtin_amdgcn_mfma_f32_16x16x32_bf16(a[m][ks], bA1, acc[0][m][1], 0, 0, 0);
        acc[1][m][0] = __builtin_amdgcn_mfma_f32_16x16x32_bf16(a[m][ks], bV0, acc[1][m][0], 0, 0, 0);
        acc[1][m][1] = __builtin_amdgcn_mfma_f32_16x16x32_bf16(a[m][ks], bV1, acc[1][m][1], 0, 0, 0);
      }
    }
    __builtin_amdgcn_s_setprio(0);
  }

  #pragma unroll
  for (int cf = 0; cf < 2; ++cf) {
    const int col = colA + cf * 16;
    const float bA = ab1[e * 512 + col];
    const float bV = vb1[e * 512 + col];
    #pragma unroll
    for (int m = 0; m < 2; ++m)
      #pragma unroll
      for (int r = 0; r < 4; ++r) {
        const int ridx = wm * 32 + m * 16 + c * 4 + r;
        if (m0 + ridx < cntE) {
          const size_t zoff = (size_t)rows[ridx] * 512 + col;
          za[zoff] = (bf16)fmaxf(acc[0][m][cf][r] + bA, 0.f);
          zv[zoff] = (bf16)fmaxf(acc[1][m][cf][r] + bV, 0.f);
        }
      }
  }
}

__global__ __launch_bounds__(256) void k_mlp2(const bf16* __restrict__ za,
    const bf16* __restrict__ zv,
    const float* __restrict__ aW2, const float* __restrict__ ab2,
    const float* __restrict__ vW2, const float* __restrict__ vb2,
    const int* __restrict__ perm, const int* __restrict__ cnt,
    float* __restrict__ out) {
  const int e = blockIdx.y;
  const int cntE = cnt[e];
  const int m0 = blockIdx.x * 64;
  if (m0 >= cntE) return;
  __shared__ bf16 Bs[48 * 520];
  const int tid = threadIdx.x;
  for (int i = tid; i < 512 * 32; i += 256) {
    const int k = i >> 5, n = i & 31;
    Bs[n * 520 + k] = (bf16)aW2[(size_t)e * 16384 + i];
  }
  for (int i = tid; i < 512; i += 256) Bs[32 * 520 + i] = (bf16)vW2[e * 512 + i];
  for (int i = tid; i < 15 * 512; i += 256) {
    const int n = 33 + (i >> 9), k = i & 511;
    Bs[n * 520 + k] = (bf16)0.f;
  }
  __syncthreads();

  const int lane = tid & 63, wave = tid >> 6;
  const int lid = lane & 15, c = lane >> 4;
  const int row0 = m0 + wave * 16;
  if (row0 >= cntE) return;
  int rowl = row0 + lid; if (rowl > cntE - 1) rowl = cntE - 1;
  const int pb = perm[e * 4096 + rowl];
  const bf16* aA = za + (size_t)pb * 512 + c * 8;
  const bf16* aV = zv + (size_t)pb * 512 + c * 8;

  f32x4 acc0 = {0.f, 0.f, 0.f, 0.f}, acc1 = acc0, accv = acc0;
  #pragma unroll
  for (int k0 = 0; k0 < 512; k0 += 32) {
    bf16x8 a1 = *(const bf16x8*)(aA + k0);
    bf16x8 a2 = *(const bf16x8*)(aV + k0);
    bf16x8 b0 = *(const bf16x8*)(&Bs[lid * 520 + k0 + c * 8]);
    bf16x8 b1 = *(const bf16x8*)(&Bs[(16 + lid) * 520 + k0 + c * 8]);
    bf16x8 b2 = *(const bf16x8*)(&Bs[(32 + lid) * 520 + k0 + c * 8]);
    acc0 = __builtin_amdgcn_mfma_f32_16x16x32_bf16(a1, b0, acc0, 0, 0, 0);
    acc1 = __builtin_amdgcn_mfma_f32_16x16x32_bf16(a1, b1, acc1, 0, 0, 0);
    accv = __builtin_amdgcn_mfma_f32_16x16x32_bf16(a2, b2, accv, 0, 0, 0);
  }

  const float ba0 = ab2[e * 32 + lid], ba1 = ab2[e * 32 + 16 + lid], bv = vb2[e];
  #pragma unroll
  for (int r = 0; r < 4; ++r) {
    const int row = row0 + c * 4 + r;
    const float y0 = acc0[r] + ba0, y1 = acc1[r] + ba1;
    float s = y0 + y1;
    s += __shfl_xor(s, 1); s += __shfl_xor(s, 2);
    s += __shfl_xor(s, 4); s += __shfl_xor(s, 8);
    const float mean = s * 0.03125f;
    const float ys = __shfl(accv[r], lane & 48) + bv;
    if (row < cntE) {
      const int bq = perm[e * 4096 + row];
      out[(size_t)bq * 32 + lid] = y0 - mean + ys;
      out[(size_t)bq * 32 + 16 + lid] = y1 - mean + ys;
    }
  }
}

extern "C" void kernel_launch(void* const* d_in, const int* in_sizes, int n_in,
                              void* d_out, int out_size, void* d_ws, size_t ws_size,
                              hipStream_t stream) {
  const float* x   = (const float*)d_in[0];
  const float* cW1 = (const float*)d_in[1];
  const float* cb1 = (const float*)d_in[2];
  const float* cW2 = (const float*)d_in[3];
  const float* cb2 = (const float*)d_in[4];
  const float* cW3 = (const float*)d_in[5];
  const float* cb3 = (const float*)d_in[6];
  const float* aW1 = (const float*)d_in[7];
  const float* ab1 = (const float*)d_in[8];
  const float* aW2 = (const float*)d_in[9];
  const float* ab2 = (const float*)d_in[10];
  const float* vW1 = (const float*)d_in[11];
  const float* vb1 = (const float*)d_in[12];
  const float* vW2 = (const float*)d_in[13];
  const float* vb2 = (const float*)d_in[14];
  const float* bd  = (const float*)d_in[15];
  float* out = (float*)d_out;

  char* ws = (char*)d_ws;
  bf16* W1T = (bf16*)(ws);                          // 8,388,608
  bf16* za  = (bf16*)(ws + 8388608ull);             // 4,194,304
  bf16* zv  = (bf16*)(ws + 12582912ull);            // 4,194,304
  bf16* h3  = (bf16*)(ws + 16777216ull);            // 8,388,608
  bf16* W1p = (bf16*)(ws + 25165824ull);            // 16,384
  bf16* W2p = (bf16*)(ws + 25182208ull);            // 65,536
  bf16* W3p = (bf16*)(ws + 25247744ull);            // 73,728
  int* perm = (int*)(ws + 25321472ull);             // 65,536
  int* cnt  = (int*)(ws + 25387008ull);             // 64
  int* ecls = (int*)(ws + 25387072ull);             // 16,384

  k_pre<<<304, 256, 0, stream>>>(cW1, cW2, cW3, W1p, W2p, W3p);
  k_front<<<5136, 256, 0, stream>>>(x, bd, ecls, aW1, vW1, W1T,
                                    W1p, cb1, W2p, cb2, W3p, cb3, h3);
  k_route_scan<<<1, 1024, 0, stream>>>(ecls, perm, cnt);
  k_mlp1<<<dim3(64, 4, 4), 512, 0, stream>>>(h3, W1T, ab1, vb1, perm, cnt, za, zv);
  k_mlp2<<<dim3(64, 4), 256, 0, stream>>>(za, zv, aW2, ab2, vW2, vb2, perm, cnt, out);
}